// Round 5
// baseline (412.375 us; speedup 1.0000x reference)
//
#include <hip/hip_runtime.h>
#include <cstdint>
#include <cstddef>

#define S_ 2048
#define B_ 4
#define H_ 16
#define ALPHA_Q 0.14724394f  // SCALE * log2(e)

typedef __attribute__((ext_vector_type(8))) __bf16 bf16x8;
typedef __attribute__((ext_vector_type(4))) __bf16 bf16x4;
typedef __attribute__((ext_vector_type(4))) float f32x4;
typedef __attribute__((ext_vector_type(16))) float f32x16;

__device__ __forceinline__ f32x16 mfma32(bf16x8 a, bf16x8 b, f32x16 c) {
  return __builtin_amdgcn_mfma_f32_32x32x16_bf16(a, b, c, 0, 0, 0);
}

// async global->LDS, 16B per lane. LDS base must be wave-uniform (HW writes
// base + lane*16); global src is per-lane.
__device__ __forceinline__ void gll16(const void* g, void* l) {
  __builtin_amdgcn_global_load_lds(
      (__attribute__((address_space(1))) void*)(uintptr_t)g,
      (__attribute__((address_space(3))) void*)(uint32_t)(uintptr_t)l,
      16, 0, 0);
}

// v_cvt_pk_bf16_f32: packs (bf16(lo), bf16(hi)) into one dword (lo in bits 0-15)
__device__ __forceinline__ int cvtpk(float lo, float hi) {
  int r;
  asm("v_cvt_pk_bf16_f32 %0, %1, %2" : "=v"(r) : "v"(lo), "v"(hi));
  return r;
}

union PAU { int w[4]; bf16x8 v; };

// Build one 32x32x16 B-operand fragment of P^T (col=q=lane&31, k=8*hi+e)
// from 8 in-lane P values (crow order). Cross-half exchange via shfl_xor(32).
__device__ __forceinline__ bf16x8 packPA(int hi, float a0, float a1, float a2,
                                         float a3, float b0, float b1, float b2,
                                         float b3) {
  const int Ylo = cvtpk(a0, a1);
  const int Yhi = cvtpk(a2, a3);
  const int Xlo = cvtpk(b0, b1);
  const int Xhi = cvtpk(b2, b3);
  const int t0 = __shfl_xor(hi ? Ylo : Xlo, 32);
  const int t1 = __shfl_xor(hi ? Yhi : Xhi, 32);
  PAU u;
  u.w[0] = hi ? t0 : Ylo;
  u.w[1] = hi ? t1 : Yhi;
  u.w[2] = hi ? Xlo : t0;
  u.w[3] = hi ? Xhi : t1;
  return u.v;
}

// ---------------- prep kernels ----------------

__global__ __launch_bounds__(256) void mla_cvt_x(const float* __restrict__ x,
                                                 __bf16* __restrict__ xb) {
  const size_t i = ((size_t)blockIdx.x * 256 + threadIdx.x) * 8;
  float4 a = *(const float4*)&x[i];
  float4 b = *(const float4*)&x[i + 4];
  bf16x8 v;
  v[0] = (__bf16)a.x; v[1] = (__bf16)a.y; v[2] = (__bf16)a.z; v[3] = (__bf16)a.w;
  v[4] = (__bf16)b.x; v[5] = (__bf16)b.y; v[6] = (__bf16)b.z; v[7] = (__bf16)b.w;
  *(bf16x8*)&xb[i] = v;
}

// W (K x N, f32, row-major) -> WT (N x K, bf16, row-major)
__global__ void mla_transpose(const float* __restrict__ W, __bf16* __restrict__ WT,
                              int K, int N) {
  __shared__ float tile[32][33];
  const int n0 = blockIdx.x * 32, k0 = blockIdx.y * 32;
  const int tx = threadIdx.x, ty = threadIdx.y;
#pragma unroll
  for (int i = 0; i < 32; i += 8)
    tile[ty + i][tx] = W[(size_t)(k0 + ty + i) * N + n0 + tx];
  __syncthreads();
#pragma unroll
  for (int i = 0; i < 32; i += 8)
    WT[(size_t)(n0 + ty + i) * K + k0 + tx] = (__bf16)tile[tx][ty + i];
}

__global__ void mla_bias(const float* __restrict__ b_dq, const float* __restrict__ b_dkv,
                         const float* __restrict__ b_kr, const float* __restrict__ b_uq,
                         const float* __restrict__ b_qr, const float* __restrict__ b_uk,
                         const float* __restrict__ b_uv, float* __restrict__ bias_d,
                         float* __restrict__ bias_uq, float* __restrict__ bias_ukv) {
  const int t = blockIdx.x * 256 + threadIdx.x;
  if (t < 384)
    bias_d[t] = (t < 128) ? b_dq[t] : (t < 256) ? b_dkv[t - 128]
               : (t < 288) ? b_kr[t - 256] : 0.f;
  if (t < 1536) bias_uq[t] = (t < 1024) ? b_uq[t] : b_qr[t - 1024];
  if (t < 2048) bias_ukv[t] = (t < 1024) ? b_uk[t] : b_uv[t - 1024];
}

__global__ void mla_rope_tab(float* __restrict__ c, float* __restrict__ sn) {
  const int t = blockIdx.x * 256 + threadIdx.x;  // t < S_*16
  const int s = t >> 4, i = t & 15;
  const float inv = exp2f(-(float)i * (13.287712379549449f / 16.0f));
  const float ang = (float)s * inv;
  c[t] = cosf(ang);
  sn[t] = sinf(ang);
}

// ---------------- mfma32 GEMM: C = A(MxK) * BT^T + bias ----------------
// 128x128 tile, BK=64, 4 waves 2x2 (each 64x64). LDS [slice][row][8]
// conflict-free layout (R4-attn-proven). 2-barrier m97 structure.
// MODE 0: bf16 out (C0, ldc).  MODE 1: f32 out (C0, ldc).
// MODE 2 (up-q): col<1024 -> qt[(b,h,s),d]*ALPHA_Q ; col>=1024 -> qr[row][c-1024]
// MODE 3 (up-kv): col<1024 -> ktb[(b,h,s),d] ; col>=1024 -> vv[row][c-1024]
template <int MODE>
__global__ __launch_bounds__(256) void gemm32(
    const __bf16* __restrict__ A, int lda, const __bf16* __restrict__ BT, int ldbt,
    const float* __restrict__ bias, void* __restrict__ C0, void* __restrict__ C1,
    int ldc, int K) {
  const int n0 = blockIdx.x * 128;
  const int m0 = blockIdx.y * 128;
  const int wave = threadIdx.x >> 6, lane = threadIdx.x & 63;
  const int hi = lane >> 5, lq = lane & 31;
  const int wm = (wave >> 1) * 64, wn = (wave & 1) * 64;
  __shared__ __bf16 __attribute__((aligned(16))) ldsA[8 * 128 * 8];  // 16 KB
  __shared__ __bf16 __attribute__((aligned(16))) ldsB[8 * 128 * 8];  // 16 KB

  const f32x16 fz16 = {0.f, 0.f, 0.f, 0.f, 0.f, 0.f, 0.f, 0.f,
                       0.f, 0.f, 0.f, 0.f, 0.f, 0.f, 0.f, 0.f};
  f32x16 acc00 = fz16, acc01 = fz16, acc10 = fz16, acc11 = fz16;

  for (int k0 = 0; k0 < K; k0 += 64) {
    __syncthreads();  // prev iteration's LDS reads done
#pragma unroll
    for (int i = 0; i < 8; ++i) {
      const int c = wave * 8 + i;  // 0..31: 16 A chunks then 16 B chunks
      if (c < 16) {
        const int sl = c >> 1, half = c & 1;
        gll16(&A[(size_t)(m0 + half * 64 + lane) * lda + k0 + sl * 8],
              &ldsA[(sl * 128 + half * 64) * 8]);
      } else {
        const int cc = c - 16;
        const int sl = cc >> 1, half = cc & 1;
        gll16(&BT[(size_t)(n0 + half * 64 + lane) * ldbt + k0 + sl * 8],
              &ldsB[(sl * 128 + half * 64) * 8]);
      }
    }
    __syncthreads();  // staged data visible

#pragma unroll
    for (int ks = 0; ks < 4; ++ks) {
      const int sl = ks * 2 + hi;  // k = ks*16 + hi*8
      bf16x8 a0 = *(const bf16x8*)&ldsA[(sl * 128 + wm + lq) * 8];
      bf16x8 a1 = *(const bf16x8*)&ldsA[(sl * 128 + wm + 32 + lq) * 8];
      bf16x8 b0 = *(const bf16x8*)&ldsB[(sl * 128 + wn + lq) * 8];
      bf16x8 b1 = *(const bf16x8*)&ldsB[(sl * 128 + wn + 32 + lq) * 8];
      acc00 = mfma32(a0, b0, acc00);
      acc01 = mfma32(a0, b1, acc01);
      acc10 = mfma32(a1, b0, acc10);
      acc11 = mfma32(a1, b1, acc11);
    }
  }

  const f32x16* accs[2][2] = {{&acc00, &acc01}, {&acc10, &acc11}};
#pragma unroll
  for (int ni = 0; ni < 2; ++ni) {
    const int col = n0 + wn + ni * 32 + lq;
    const float bv = bias[col];
#pragma unroll
    for (int mi = 0; mi < 2; ++mi) {
      const f32x16& ac = *accs[mi][ni];
#pragma unroll
      for (int r = 0; r < 16; ++r) {
        const int row = m0 + wm + mi * 32 + (r & 3) + 8 * (r >> 2) + 4 * hi;
        const float v = ac[r] + bv;
        if (MODE == 0) {
          ((__bf16*)C0)[(size_t)row * ldc + col] = (__bf16)v;
        } else if (MODE == 1) {
          ((float*)C0)[(size_t)row * ldc + col] = v;
        } else {
          const int b = row >> 11, s = row & 2047;
          if (col < 1024) {
            const int h = col >> 6, d = col & 63;
            const size_t o = ((size_t)(b * H_ + h) * S_ + s) * 96 + d;
            if (MODE == 2)
              ((__bf16*)C0)[o] = (__bf16)(v * ALPHA_Q);
            else
              ((__bf16*)C0)[o] = (__bf16)v;
          } else {
            if (MODE == 2)
              ((__bf16*)C1)[(size_t)row * 512 + col - 1024] = (__bf16)v;
            else
              ((__bf16*)C1)[(size_t)row * 1024 + col - 1024] = (__bf16)v;
          }
        }
      }
    }
  }
}

// ---------------- glue: RoPE for q_r and k_r into qt/ktb ----------------
// thread -> (bs, h, i): q pair from qr, k pair from cqkvr (broadcast over h).
__global__ __launch_bounds__(256) void mla_rope_qk(
    const __bf16* __restrict__ qr, const __bf16* __restrict__ cqkvr,
    const float* __restrict__ ropec, const float* __restrict__ ropes,
    __bf16* __restrict__ qt, __bf16* __restrict__ ktb) {
  const int gid = blockIdx.x * 256 + threadIdx.x;  // < 8192*256
  const int bs = gid >> 8;
  const int h = (gid >> 4) & 15;
  const int i = gid & 15;
  const int b = bs >> 11, s = bs & 2047;
  const float c = ropec[s * 16 + i], sn = ropes[s * 16 + i];
  const size_t o = ((size_t)(b * H_ + h) * S_ + s) * 96 + 64 + 2 * i;
  {
    const float r = (float)qr[(size_t)bs * 512 + h * 32 + 2 * i];
    const float im = (float)qr[(size_t)bs * 512 + h * 32 + 2 * i + 1];
    qt[o] = (__bf16)((r * c - im * sn) * ALPHA_Q);
    qt[o + 1] = (__bf16)((r * sn + im * c) * ALPHA_Q);
  }
  {
    const float r = (float)cqkvr[(size_t)bs * 384 + 256 + 2 * i];
    const float im = (float)cqkvr[(size_t)bs * 384 + 256 + 2 * i + 1];
    ktb[o] = (__bf16)(r * c - im * sn);
    ktb[o + 1] = (__bf16)(r * sn + im * c);
  }
}

// ---------------- glue: V (vv: 8192 x 1024) -> V^T (B,H,64,S) ----------------
__global__ __launch_bounds__(256) void mla_vtrans(const __bf16* __restrict__ vv,
                                                  __bf16* __restrict__ vt) {
  const int s0 = blockIdx.x * 64;
  const int bh = blockIdx.y;
  const int b = bh >> 4, h = bh & 15;
  __shared__ __bf16 __attribute__((aligned(16))) tile[64][72];
  const int t = threadIdx.x;
  {
    const int r = t >> 2, c0 = (t & 3) * 16;
    const size_t src = (size_t)(b * S_ + s0 + r) * 1024 + h * 64 + c0;
    bf16x8 u0 = *(const bf16x8*)&vv[src];
    bf16x8 u1 = *(const bf16x8*)&vv[src + 8];
    *(bf16x8*)&tile[r][c0] = u0;
    *(bf16x8*)&tile[r][c0 + 8] = u1;
  }
  __syncthreads();
  {
    const int d = t >> 2, sc0 = (t & 3) * 16;
    bf16x8 w0, w1;
#pragma unroll
    for (int e = 0; e < 8; ++e) {
      w0[e] = tile[sc0 + e][d];
      w1[e] = tile[sc0 + 8 + e][d];
    }
    const size_t dst = ((size_t)bh * 64 + d) * S_ + s0 + sc0;
    *(bf16x8*)&vt[dst] = w0;
    *(bf16x8*)&vt[dst + 8] = w1;
  }
}

// ---------------- causal flash attention (32x32 MFMA, unchanged R4) --------
__global__ __launch_bounds__(256, 3) void mla_attn(const __bf16* __restrict__ qt,
                                                   const __bf16* __restrict__ kt,
                                                   const __bf16* __restrict__ vt,
                                                   __bf16* __restrict__ ao) {
  const int qblk = (int)gridDim.x - 1 - blockIdx.x;  // heavy blocks first
  const int bh = blockIdx.y;
  const int wave = threadIdx.x >> 6, lane = threadIdx.x & 63;
  const int hi = lane >> 5, lq = lane & 31;
  const int q0w = qblk * 128 + wave * 32;
  const __bf16* Q = qt + (size_t)bh * S_ * 96;
  const __bf16* Kp = kt + (size_t)bh * S_ * 96;
  const __bf16* Vp = vt + (size_t)bh * 64 * S_;

  __shared__ __bf16 __attribute__((aligned(16))) kbuf[2][12 * 512];
  __shared__ __bf16 __attribute__((aligned(16))) vbuf[2][8 * 512];

  bf16x8 qf[6];
#pragma unroll
  for (int kd = 0; kd < 6; ++kd)
    qf[kd] = *(const bf16x8*)&Q[(size_t)(q0w + lq) * 96 + kd * 16 + hi * 8];

  const f32x16 fz16 = {0.f, 0.f, 0.f, 0.f, 0.f, 0.f, 0.f, 0.f,
                       0.f, 0.f, 0.f, 0.f, 0.f, 0.f, 0.f, 0.f};
  f32x16 o0 = fz16, o1 = fz16;
  float m = -3.0e38f, L = 0.f;

  const int tEnd = (q0w + 31) >> 6;
  const int tMax = qblk * 2 + 1;

  auto stage = [&](int t, int bsel) {
    const int kv0 = t * 64;
#pragma unroll
    for (int i = 0; i < 5; ++i) {
      const int c = wave + 4 * i;
      if (c < 12)
        gll16(&Kp[(size_t)(kv0 + lane) * 96 + c * 8], &kbuf[bsel][c * 512]);
      else
        gll16(&Vp[(size_t)lane * S_ + kv0 + (c - 12) * 8], &vbuf[bsel][(c - 12) * 512]);
    }
  };

  stage(0, 0);
  __syncthreads();

  int bsel = 0;
  for (int t = 0; t <= tMax; ++t) {
    if (t < tMax) stage(t + 1, bsel ^ 1);
    if (t <= tEnd) {
      f32x16 s0 = fz16, s1 = fz16;
#pragma unroll
      for (int kd = 0; kd < 6; ++kd) {
        const int sl = kd * 2 + hi;
        bf16x8 a0 = *(const bf16x8*)&kbuf[bsel][(sl * 64 + lq) * 8];
        bf16x8 a1 = *(const bf16x8*)&kbuf[bsel][(sl * 64 + 32 + lq) * 8];
        s0 = mfma32(a0, qf[kd], s0);
        s1 = mfma32(a1, qf[kd], s1);
      }
      if (t == tEnd) {
        const int qg = q0w + lq;
        const int kvb = t * 64 + 4 * hi;
#pragma unroll
        for (int r = 0; r < 16; ++r) {
          const int crow = (r & 3) + 8 * (r >> 2);
          if (kvb + crow > qg) s0[r] = -3.0e38f;
          if (kvb + 32 + crow > qg) s1[r] = -3.0e38f;
        }
      }
      float tm = s0[0];
#pragma unroll
      for (int r = 1; r < 16; ++r) tm = fmaxf(tm, s0[r]);
#pragma unroll
      for (int r = 0; r < 16; ++r) tm = fmaxf(tm, s1[r]);
      tm = fmaxf(tm, __shfl_xor(tm, 32));
      const float mnew = fmaxf(m, tm);
      float p0[16], p1[16];
      float ps = 0.f;
#pragma unroll
      for (int r = 0; r < 16; ++r) {
        p0[r] = exp2f(s0[r] - mnew);
        p1[r] = exp2f(s1[r] - mnew);
        ps += p0[r] + p1[r];
      }
      ps += __shfl_xor(ps, 32);
      const float sc = exp2f(m - mnew);
      L = L * sc + ps;
      m = mnew;
      o0 *= sc;
      o1 *= sc;
      bf16x8 pa[4];
      pa[0] = packPA(hi, p0[0], p0[1], p0[2], p0[3], p0[4], p0[5], p0[6], p0[7]);
      pa[1] = packPA(hi, p0[8], p0[9], p0[10], p0[11], p0[12], p0[13], p0[14], p0[15]);
      pa[2] = packPA(hi, p1[0], p1[1], p1[2], p1[3], p1[4], p1[5], p1[6], p1[7]);
      pa[3] = packPA(hi, p1[8], p1[9], p1[10], p1[11], p1[12], p1[13], p1[14], p1[15]);
#pragma unroll
      for (int ks = 0; ks < 4; ++ks) {
        const int sl = ks * 2 + hi;
        bf16x8 v0 = *(const bf16x8*)&vbuf[bsel][(sl * 64 + lq) * 8];
        bf16x8 v1 = *(const bf16x8*)&vbuf[bsel][(sl * 64 + 32 + lq) * 8];
        o0 = mfma32(v0, pa[ks], o0);
        o1 = mfma32(v1, pa[ks], o1);
      }
    }
    __syncthreads();
    bsel ^= 1;
  }

  const float invL = 1.0f / L;
  const int bb = bh >> 4, h = bh & 15;
  __bf16* aorow = ao + (size_t)(bb * S_ + q0w + lq) * 1024 + h * 64;
#pragma unroll
  for (int rr = 0; rr < 4; ++rr) {
    bf16x4 w0, w1;
#pragma unroll
    for (int j = 0; j < 4; ++j) {
      w0[j] = (__bf16)(o0[4 * rr + j] * invL);
      w1[j] = (__bf16)(o1[4 * rr + j] * invL);
    }
    *(bf16x4*)&aorow[rr * 8 + 4 * hi] = w0;
    *(bf16x4*)&aorow[32 + rr * 8 + 4 * hi] = w1;
  }
}

// ---------------- launcher ----------------
extern "C" void kernel_launch(void* const* d_in, const int* in_sizes, int n_in,
                              void* d_out, int out_size, void* d_ws, size_t ws_size,
                              hipStream_t stream) {
  (void)in_sizes; (void)n_in; (void)out_size; (void)ws_size;
  const float* x = (const float*)d_in[0];
  // d_in[1] = mask (tril ones) -> causal handled analytically
  const float* W_dkv = (const float*)d_in[2];
  const float* b_dkv = (const float*)d_in[3];
  const float* W_dq = (const float*)d_in[4];
  const float* b_dq = (const float*)d_in[5];
  const float* W_uk = (const float*)d_in[6];
  const float* b_uk = (const float*)d_in[7];
  const float* W_uv = (const float*)d_in[8];
  const float* b_uv = (const float*)d_in[9];
  const float* W_uq = (const float*)d_in[10];
  const float* b_uq = (const float*)d_in[11];
  const float* W_qr = (const float*)d_in[12];
  const float* b_qr = (const float*)d_in[13];
  const float* W_kr = (const float*)d_in[14];
  const float* b_kr = (const float*)d_in[15];
  const float* W_o = (const float*)d_in[16];
  const float* b_o = (const float*)d_in[17];
  float* out = (float*)d_out;

  char* ws = (char*)d_ws;
  size_t off = 0;
  auto take = [&](size_t nbytes) -> char* {
    char* p = ws + off;
    off += (nbytes + 255) & ~(size_t)255;
    return p;
  };
  __bf16* xb = (__bf16*)take((size_t)8192 * 1024 * 2);
  __bf16* WdT = (__bf16*)take((size_t)384 * 1024 * 2);     // [Wdq|Wdkv|Wkr|pad]^T
  __bf16* WuqT = (__bf16*)take((size_t)1536 * 128 * 2);    // [Wuq|Wqr]^T
  __bf16* WukvT = (__bf16*)take((size_t)2048 * 128 * 2);   // [Wuk|Wuv]^T
  __bf16* WoT = (__bf16*)take((size_t)1024 * 1024 * 2);
  float* bias_d = (float*)take(384 * 4);
  float* bias_uq = (float*)take(1536 * 4);
  float* bias_ukv = (float*)take(2048 * 4);
  float* ropec = (float*)take((size_t)S_ * 16 * 4);
  float* ropes = (float*)take((size_t)S_ * 16 * 4);
  __bf16* cqkvr = (__bf16*)take((size_t)8192 * 384 * 2);   // [c_q|c_kv|k_r|pad]
  __bf16* qr = (__bf16*)take((size_t)8192 * 512 * 2);      // raw q_r (pre-RoPE)
  __bf16* vv = (__bf16*)take((size_t)8192 * 1024 * 2);     // raw v
  __bf16* qt = (__bf16*)take((size_t)B_ * H_ * S_ * 96 * 2);
  __bf16* ktb = (__bf16*)take((size_t)B_ * H_ * S_ * 96 * 2);
  __bf16* vt = (__bf16*)take((size_t)B_ * H_ * 64 * S_ * 2);
  __bf16* aout = (__bf16*)take((size_t)8192 * 1024 * 2);

  // zero the padded rows of WdT (cols 288..383 of down-proj output)
  hipMemsetAsync(WdT + (size_t)288 * 1024, 0, (size_t)96 * 1024 * 2, stream);

  mla_cvt_x<<<4096, 256, 0, stream>>>(x, xb);
  mla_transpose<<<dim3(4, 32), dim3(32, 8), 0, stream>>>(W_dq, WdT, 1024, 128);
  mla_transpose<<<dim3(4, 32), dim3(32, 8), 0, stream>>>(W_dkv, WdT + (size_t)128 * 1024, 1024, 128);
  mla_transpose<<<dim3(1, 32), dim3(32, 8), 0, stream>>>(W_kr, WdT + (size_t)256 * 1024, 1024, 32);
  mla_transpose<<<dim3(32, 4), dim3(32, 8), 0, stream>>>(W_uq, WuqT, 128, 1024);
  mla_transpose<<<dim3(16, 4), dim3(32, 8), 0, stream>>>(W_qr, WuqT + (size_t)1024 * 128, 128, 512);
  mla_transpose<<<dim3(32, 4), dim3(32, 8), 0, stream>>>(W_uk, WukvT, 128, 1024);
  mla_transpose<<<dim3(32, 4), dim3(32, 8), 0, stream>>>(W_uv, WukvT + (size_t)1024 * 128, 128, 1024);
  mla_transpose<<<dim3(32, 32), dim3(32, 8), 0, stream>>>(W_o, WoT, 1024, 1024);
  mla_bias<<<8, 256, 0, stream>>>(b_dq, b_dkv, b_kr, b_uq, b_qr, b_uk, b_uv,
                                  bias_d, bias_uq, bias_ukv);
  mla_rope_tab<<<(S_ * 16) / 256, 256, 0, stream>>>(ropec, ropes);

  // down-proj: x(8192x1024) @ [Wdq|Wdkv|Wkr] -> cqkvr (8192x384)
  gemm32<0><<<dim3(3, 64), 256, 0, stream>>>(xb, 1024, WdT, 1024, bias_d,
                                             cqkvr, nullptr, 384, 1024);
  // up-proj q: c_q @ [Wuq|Wqr] -> qt (q_c, scaled) + qr (q_r raw)
  gemm32<2><<<dim3(12, 64), 256, 0, stream>>>(cqkvr, 384, WuqT, 128, bias_uq,
                                              qt, qr, 0, 128);
  // up-proj kv: c_kv @ [Wuk|Wuv] -> ktb (k_c) + vv (v raw)
  gemm32<3><<<dim3(16, 64), 256, 0, stream>>>(cqkvr + 128, 384, WukvT, 128,
                                              bias_ukv, ktb, vv, 0, 128);

  mla_rope_qk<<<8192, 256, 0, stream>>>(qr, cqkvr, ropec, ropes, qt, ktb);
  mla_vtrans<<<dim3(32, 64), 256, 0, stream>>>(vv, vt);
  mla_attn<<<dim3(16, 64), 256, 0, stream>>>(qt, ktb, vt, aout);

  // final: aout(8192x1024) @ W_o + b_o -> out f32
  gemm32<1><<<dim3(8, 64), 256, 0, stream>>>(aout, 1024, WoT, 1024, b_o, out,
                                             nullptr, 1024, 1024);
}

// Round 7
// 388.306 us; speedup vs baseline: 1.0620x; 1.0620x over previous
//
#include <hip/hip_runtime.h>
#include <cstdint>
#include <cstddef>

#define S_ 2048
#define B_ 4
#define H_ 16
#define ALPHA_Q 0.14724394f  // SCALE * log2(e)

typedef __attribute__((ext_vector_type(8))) __bf16 bf16x8;
typedef __attribute__((ext_vector_type(4))) __bf16 bf16x4;
typedef __attribute__((ext_vector_type(4))) float f32x4;
typedef __attribute__((ext_vector_type(16))) float f32x16;

__device__ __forceinline__ f32x16 mfma32(bf16x8 a, bf16x8 b, f32x16 c) {
  return __builtin_amdgcn_mfma_f32_32x32x16_bf16(a, b, c, 0, 0, 0);
}

// async global->LDS, 16B per lane. LDS base must be wave-uniform (HW writes
// base + lane*16); global src is per-lane.
__device__ __forceinline__ void gll16(const void* g, void* l) {
  __builtin_amdgcn_global_load_lds(
      (__attribute__((address_space(1))) void*)(uintptr_t)g,
      (__attribute__((address_space(3))) void*)(uint32_t)(uintptr_t)l,
      16, 0, 0);
}

// v_cvt_pk_bf16_f32: packs (bf16(lo), bf16(hi)) into one dword (lo in bits 0-15)
__device__ __forceinline__ int cvtpk(float lo, float hi) {
  int r;
  asm("v_cvt_pk_bf16_f32 %0, %1, %2" : "=v"(r) : "v"(lo), "v"(hi));
  return r;
}

union PAU { int w[4]; bf16x8 v; };

// Build one 32x32x16 B-operand fragment of P^T (col=q=lane&31, k=8*hi+e)
// from 8 in-lane P values (crow order). Cross-half exchange via shfl_xor(32).
__device__ __forceinline__ bf16x8 packPA(int hi, float a0, float a1, float a2,
                                         float a3, float b0, float b1, float b2,
                                         float b3) {
  const int Ylo = cvtpk(a0, a1);
  const int Yhi = cvtpk(a2, a3);
  const int Xlo = cvtpk(b0, b1);
  const int Xhi = cvtpk(b2, b3);
  const int t0 = __shfl_xor(hi ? Ylo : Xlo, 32);
  const int t1 = __shfl_xor(hi ? Yhi : Xhi, 32);
  PAU u;
  u.w[0] = hi ? t0 : Ylo;
  u.w[1] = hi ? t1 : Yhi;
  u.w[2] = hi ? Xlo : t0;
  u.w[3] = hi ? Xhi : t1;
  return u.v;
}

// depth-5 tree max of one f32x16 (no fast-math -> must write the tree)
__device__ __forceinline__ float tmax16(const f32x16& v) {
  float a[8];
#pragma unroll
  for (int i = 0; i < 8; ++i) a[i] = fmaxf(v[i], v[i + 8]);
#pragma unroll
  for (int s = 4; s > 0; s >>= 1)
#pragma unroll
    for (int i = 0; i < s; ++i) a[i] = fmaxf(a[i], a[i + s]);
  return a[0];
}

// ---------------- fused prep kernel ----------------
// tile-id dispatch: [0,4096) cvt_x ; [4096,5856) weight transposes ;
// [5856,5984) rope tables ; [5984,6000) bias concat.
__global__ __launch_bounds__(256) void mla_prep(
    const float* __restrict__ x, __bf16* __restrict__ xb,
    const float* __restrict__ W_dq, const float* __restrict__ W_dkv,
    const float* __restrict__ W_kr, const float* __restrict__ W_uq,
    const float* __restrict__ W_qr, const float* __restrict__ W_uk,
    const float* __restrict__ W_uv, const float* __restrict__ W_o,
    __bf16* __restrict__ WdT, __bf16* __restrict__ WuqT,
    __bf16* __restrict__ WukvT, __bf16* __restrict__ WoT,
    const float* __restrict__ b_dq, const float* __restrict__ b_dkv,
    const float* __restrict__ b_kr, const float* __restrict__ b_uq,
    const float* __restrict__ b_qr, const float* __restrict__ b_uk,
    const float* __restrict__ b_uv, float* __restrict__ bias_d,
    float* __restrict__ bias_uq, float* __restrict__ bias_ukv,
    float* __restrict__ ropec, float* __restrict__ ropes) {
  const int id = blockIdx.x;
  const int t = threadIdx.x;
  __shared__ float tile[32][33];

  if (id < 4096) {  // x f32 -> bf16
    const size_t i = ((size_t)id * 256 + t) * 8;
    float4 a = *(const float4*)&x[i];
    float4 b = *(const float4*)&x[i + 4];
    bf16x8 v;
    v[0] = (__bf16)a.x; v[1] = (__bf16)a.y; v[2] = (__bf16)a.z; v[3] = (__bf16)a.w;
    v[4] = (__bf16)b.x; v[5] = (__bf16)b.y; v[6] = (__bf16)b.z; v[7] = (__bf16)b.w;
    *(bf16x8*)&xb[i] = v;
    return;
  }
  if (id < 5856) {  // W (KxN f32) -> WT (NxK bf16)
    int rel = id - 4096;
    const float* W;
    __bf16* WT;
    int K, N, nt;
    if (rel < 128)      { W = W_dq;  WT = WdT;                      K = 1024; N = 128;  nt = 4; }
    else if (rel < 256) { W = W_dkv; WT = WdT + (size_t)128 * 1024; K = 1024; N = 128;  nt = 4;  rel -= 128; }
    else if (rel < 288) { W = W_kr;  WT = WdT + (size_t)256 * 1024; K = 1024; N = 32;   nt = 1;  rel -= 256; }
    else if (rel < 416) { W = W_uq;  WT = WuqT;                     K = 128;  N = 1024; nt = 32; rel -= 288; }
    else if (rel < 480) { W = W_qr;  WT = WuqT + (size_t)1024 * 128; K = 128; N = 512;  nt = 16; rel -= 416; }
    else if (rel < 608) { W = W_uk;  WT = WukvT;                    K = 128;  N = 1024; nt = 32; rel -= 480; }
    else if (rel < 736) { W = W_uv;  WT = WukvT + (size_t)1024 * 128; K = 128; N = 1024; nt = 32; rel -= 608; }
    else                { W = W_o;   WT = WoT;                      K = 1024; N = 1024; nt = 32; rel -= 736; }
    const int n0 = (rel % nt) * 32, k0 = (rel / nt) * 32;
    const int tx = t & 31, ty = t >> 5;
#pragma unroll
    for (int i = 0; i < 32; i += 8)
      tile[ty + i][tx] = W[(size_t)(k0 + ty + i) * N + n0 + tx];
    __syncthreads();
#pragma unroll
    for (int i = 0; i < 32; i += 8)
      WT[(size_t)(n0 + ty + i) * K + k0 + tx] = (__bf16)tile[tx][ty + i];
    return;
  }
  if (id < 5984) {  // rope tables
    const int g = (id - 5856) * 256 + t;  // < S_*16
    const int s = g >> 4, i = g & 15;
    const float inv = exp2f(-(float)i * (13.287712379549449f / 16.0f));
    const float ang = (float)s * inv;
    ropec[g] = cosf(ang);
    ropes[g] = sinf(ang);
    return;
  }
  {  // bias concat
    const int g = (id - 5984) * 256 + t;
    if (g < 384)
      bias_d[g] = (g < 128) ? b_dq[g] : (g < 256) ? b_dkv[g - 128]
                 : (g < 288) ? b_kr[g - 256] : 0.f;
    if (g < 1536) bias_uq[g] = (g < 1024) ? b_uq[g] : b_qr[g - 1024];
    if (g < 2048) bias_ukv[g] = (g < 1024) ? b_uk[g] : b_uv[g - 1024];
  }
}

// ---------------- mfma32 GEMM: C = A(MxK) * BT^T + bias ----------------
// 128x128 tile, BK=64, 4 waves 2x2 (each 64x64). LDS [slice][row][8]
// conflict-free layout. 2-barrier m97 structure.
// MODE 0: bf16 out. MODE 1: f32 out.
// MODE 2 (up-q): col<1024 -> qt[(b,h,s),d]*ALPHA_Q ; col>=1024 -> qr
// MODE 3 (up-kv): col<1024 -> ktb[(b,h,s),d] ; col>=1024 -> vv
template <int MODE>
__global__ __launch_bounds__(256) void gemm32(
    const __bf16* __restrict__ A, int lda, const __bf16* __restrict__ BT, int ldbt,
    const float* __restrict__ bias, void* __restrict__ C0, void* __restrict__ C1,
    int ldc, int K) {
  const int n0 = blockIdx.x * 128;
  const int m0 = blockIdx.y * 128;
  const int wave = threadIdx.x >> 6, lane = threadIdx.x & 63;
  const int hi = lane >> 5, lq = lane & 31;
  const int wm = (wave >> 1) * 64, wn = (wave & 1) * 64;
  __shared__ __bf16 __attribute__((aligned(16))) ldsA[8 * 128 * 8];  // 16 KB
  __shared__ __bf16 __attribute__((aligned(16))) ldsB[8 * 128 * 8];  // 16 KB

  const f32x16 fz16 = {0.f, 0.f, 0.f, 0.f, 0.f, 0.f, 0.f, 0.f,
                       0.f, 0.f, 0.f, 0.f, 0.f, 0.f, 0.f, 0.f};
  f32x16 acc00 = fz16, acc01 = fz16, acc10 = fz16, acc11 = fz16;

  for (int k0 = 0; k0 < K; k0 += 64) {
    __syncthreads();
#pragma unroll
    for (int i = 0; i < 8; ++i) {
      const int c = wave * 8 + i;
      if (c < 16) {
        const int sl = c >> 1, half = c & 1;
        gll16(&A[(size_t)(m0 + half * 64 + lane) * lda + k0 + sl * 8],
              &ldsA[(sl * 128 + half * 64) * 8]);
      } else {
        const int cc = c - 16;
        const int sl = cc >> 1, half = cc & 1;
        gll16(&BT[(size_t)(n0 + half * 64 + lane) * ldbt + k0 + sl * 8],
              &ldsB[(sl * 128 + half * 64) * 8]);
      }
    }
    __syncthreads();

#pragma unroll
    for (int ks = 0; ks < 4; ++ks) {
      const int sl = ks * 2 + hi;
      bf16x8 a0 = *(const bf16x8*)&ldsA[(sl * 128 + wm + lq) * 8];
      bf16x8 a1 = *(const bf16x8*)&ldsA[(sl * 128 + wm + 32 + lq) * 8];
      bf16x8 b0 = *(const bf16x8*)&ldsB[(sl * 128 + wn + lq) * 8];
      bf16x8 b1 = *(const bf16x8*)&ldsB[(sl * 128 + wn + 32 + lq) * 8];
      acc00 = mfma32(a0, b0, acc00);
      acc01 = mfma32(a0, b1, acc01);
      acc10 = mfma32(a1, b0, acc10);
      acc11 = mfma32(a1, b1, acc11);
    }
  }

  const f32x16* accs[2][2] = {{&acc00, &acc01}, {&acc10, &acc11}};
#pragma unroll
  for (int ni = 0; ni < 2; ++ni) {
    const int col = n0 + wn + ni * 32 + lq;
    const float bv = bias[col];
#pragma unroll
    for (int mi = 0; mi < 2; ++mi) {
      const f32x16& ac = *accs[mi][ni];
#pragma unroll
      for (int r = 0; r < 16; ++r) {
        const int row = m0 + wm + mi * 32 + (r & 3) + 8 * (r >> 2) + 4 * hi;
        const float v = ac[r] + bv;
        if (MODE == 0) {
          ((__bf16*)C0)[(size_t)row * ldc + col] = (__bf16)v;
        } else if (MODE == 1) {
          ((float*)C0)[(size_t)row * ldc + col] = v;
        } else {
          const int b = row >> 11, s = row & 2047;
          if (col < 1024) {
            const int h = col >> 6, d = col & 63;
            const size_t o = ((size_t)(b * H_ + h) * S_ + s) * 96 + d;
            if (MODE == 2)
              ((__bf16*)C0)[o] = (__bf16)(v * ALPHA_Q);
            else
              ((__bf16*)C0)[o] = (__bf16)v;
          } else {
            if (MODE == 2)
              ((__bf16*)C1)[(size_t)row * 512 + col - 1024] = (__bf16)v;
            else
              ((__bf16*)C1)[(size_t)row * 1024 + col - 1024] = (__bf16)v;
          }
        }
      }
    }
  }
}

// ---------------- fused glue: RoPE(q_r,k_r) + V transpose ----------------
// blockIdx.x < 8192: rope path ; else vtrans path (bid-8192 -> (s-tile, bh)).
__global__ __launch_bounds__(256) void mla_glue(
    const __bf16* __restrict__ qr, const __bf16* __restrict__ cqkvr,
    const float* __restrict__ ropec, const float* __restrict__ ropes,
    __bf16* __restrict__ qt, __bf16* __restrict__ ktb,
    const __bf16* __restrict__ vv, __bf16* __restrict__ vt) {
  __shared__ __bf16 __attribute__((aligned(16))) tile[64][72];
  const int t = threadIdx.x;
  if (blockIdx.x < 8192) {
    const int gid = blockIdx.x * 256 + t;
    const int bs = gid >> 8;
    const int h = (gid >> 4) & 15;
    const int i = gid & 15;
    const int b = bs >> 11, s = bs & 2047;
    const float c = ropec[s * 16 + i], sn = ropes[s * 16 + i];
    const size_t o = ((size_t)(b * H_ + h) * S_ + s) * 96 + 64 + 2 * i;
    {
      const float r = (float)qr[(size_t)bs * 512 + h * 32 + 2 * i];
      const float im = (float)qr[(size_t)bs * 512 + h * 32 + 2 * i + 1];
      qt[o] = (__bf16)((r * c - im * sn) * ALPHA_Q);
      qt[o + 1] = (__bf16)((r * sn + im * c) * ALPHA_Q);
    }
    {
      const float r = (float)cqkvr[(size_t)bs * 384 + 256 + 2 * i];
      const float im = (float)cqkvr[(size_t)bs * 384 + 256 + 2 * i + 1];
      ktb[o] = (__bf16)(r * c - im * sn);
      ktb[o + 1] = (__bf16)(r * sn + im * c);
    }
    return;
  }
  const int bid = blockIdx.x - 8192;
  const int s0 = (bid & 31) * 64;
  const int bh = bid >> 5;
  const int b = bh >> 4, h = bh & 15;
  {
    const int r = t >> 2, c0 = (t & 3) * 16;
    const size_t src = (size_t)(b * S_ + s0 + r) * 1024 + h * 64 + c0;
    bf16x8 u0 = *(const bf16x8*)&vv[src];
    bf16x8 u1 = *(const bf16x8*)&vv[src + 8];
    *(bf16x8*)&tile[r][c0] = u0;
    *(bf16x8*)&tile[r][c0 + 8] = u1;
  }
  __syncthreads();
  {
    const int d = t >> 2, sc0 = (t & 3) * 16;
    bf16x8 w0, w1;
#pragma unroll
    for (int e = 0; e < 8; ++e) {
      w0[e] = tile[sc0 + e][d];
      w1[e] = tile[sc0 + 8 + e][d];
    }
    const size_t dst = ((size_t)bh * 64 + d) * S_ + s0 + sc0;
    *(bf16x8*)&vt[dst] = w0;
    *(bf16x8*)&vt[dst + 8] = w1;
  }
}

// ---------------- causal flash attention (32x32 MFMA) ----------------
// R5 structure + tree reductions (depth-5 instead of 31-op serial chains)
// + T13 defer-max (skip rescale when max growth <= 8 in log2 domain).
__global__ __launch_bounds__(256, 3) void mla_attn(const __bf16* __restrict__ qt,
                                                   const __bf16* __restrict__ kt,
                                                   const __bf16* __restrict__ vt,
                                                   __bf16* __restrict__ ao) {
  const int qblk = (int)gridDim.x - 1 - blockIdx.x;  // heavy blocks first
  const int bh = blockIdx.y;
  const int wave = threadIdx.x >> 6, lane = threadIdx.x & 63;
  const int hi = lane >> 5, lq = lane & 31;
  const int q0w = qblk * 128 + wave * 32;
  const __bf16* Q = qt + (size_t)bh * S_ * 96;
  const __bf16* Kp = kt + (size_t)bh * S_ * 96;
  const __bf16* Vp = vt + (size_t)bh * 64 * S_;

  __shared__ __bf16 __attribute__((aligned(16))) kbuf[2][12 * 512];
  __shared__ __bf16 __attribute__((aligned(16))) vbuf[2][8 * 512];

  bf16x8 qf[6];
#pragma unroll
  for (int kd = 0; kd < 6; ++kd)
    qf[kd] = *(const bf16x8*)&Q[(size_t)(q0w + lq) * 96 + kd * 16 + hi * 8];

  const f32x16 fz16 = {0.f, 0.f, 0.f, 0.f, 0.f, 0.f, 0.f, 0.f,
                       0.f, 0.f, 0.f, 0.f, 0.f, 0.f, 0.f, 0.f};
  f32x16 o0 = fz16, o1 = fz16;
  float m = -3.0e38f, L = 0.f;

  const int tEnd = (q0w + 31) >> 6;
  const int tMax = qblk * 2 + 1;

  auto stage = [&](int t, int bsel) {
    const int kv0 = t * 64;
#pragma unroll
    for (int i = 0; i < 5; ++i) {
      const int c = wave + 4 * i;
      if (c < 12)
        gll16(&Kp[(size_t)(kv0 + lane) * 96 + c * 8], &kbuf[bsel][c * 512]);
      else
        gll16(&Vp[(size_t)lane * S_ + kv0 + (c - 12) * 8], &vbuf[bsel][(c - 12) * 512]);
    }
  };

  stage(0, 0);
  __syncthreads();

  int bsel = 0;
  for (int t = 0; t <= tMax; ++t) {
    if (t < tMax) stage(t + 1, bsel ^ 1);
    if (t <= tEnd) {
      f32x16 s0 = fz16, s1 = fz16;
#pragma unroll
      for (int kd = 0; kd < 6; ++kd) {
        const int sl = kd * 2 + hi;
        bf16x8 a0 = *(const bf16x8*)&kbuf[bsel][(sl * 64 + lq) * 8];
        bf16x8 a1 = *(const bf16x8*)&kbuf[bsel][(sl * 64 + 32 + lq) * 8];
        s0 = mfma32(a0, qf[kd], s0);
        s1 = mfma32(a1, qf[kd], s1);
      }
      if (t == tEnd) {
        const int qg = q0w + lq;
        const int kvb = t * 64 + 4 * hi;
#pragma unroll
        for (int r = 0; r < 16; ++r) {
          const int crow = (r & 3) + 8 * (r >> 2);
          if (kvb + crow > qg) s0[r] = -3.0e38f;
          if (kvb + 32 + crow > qg) s1[r] = -3.0e38f;
        }
      }
      // row max: two depth-5 trees + pair + cross-half
      float tm = fmaxf(tmax16(s0), tmax16(s1));
      tm = fmaxf(tm, __shfl_xor(tm, 32));
      // defer-max (T13): rescale only when max grew by > 8 (log2 domain)
      if (!__all(tm <= m + 8.0f)) {
        const float mnew = fmaxf(m, tm);
        const float sc = exp2f(m - mnew);
        m = mnew;
        L *= sc;
        o0 *= sc;
        o1 *= sc;
      }
      float p0[16], p1[16];
#pragma unroll
      for (int r = 0; r < 16; ++r) {
        p0[r] = exp2f(s0[r] - m);
        p1[r] = exp2f(s1[r] - m);
      }
      // sum: depth-5 tree
      float a[16];
#pragma unroll
      for (int r = 0; r < 16; ++r) a[r] = p0[r] + p1[r];
#pragma unroll
      for (int s = 8; s > 0; s >>= 1)
#pragma unroll
        for (int i = 0; i < s; ++i) a[i] += a[i + s];
      float ps = a[0];
      ps += __shfl_xor(ps, 32);
      L += ps;
      bf16x8 pa[4];
      pa[0] = packPA(hi, p0[0], p0[1], p0[2], p0[3], p0[4], p0[5], p0[6], p0[7]);
      pa[1] = packPA(hi, p0[8], p0[9], p0[10], p0[11], p0[12], p0[13], p0[14], p0[15]);
      pa[2] = packPA(hi, p1[0], p1[1], p1[2], p1[3], p1[4], p1[5], p1[6], p1[7]);
      pa[3] = packPA(hi, p1[8], p1[9], p1[10], p1[11], p1[12], p1[13], p1[14], p1[15]);
#pragma unroll
      for (int ks = 0; ks < 4; ++ks) {
        const int sl = ks * 2 + hi;
        bf16x8 v0 = *(const bf16x8*)&vbuf[bsel][(sl * 64 + lq) * 8];
        bf16x8 v1 = *(const bf16x8*)&vbuf[bsel][(sl * 64 + 32 + lq) * 8];
        o0 = mfma32(v0, pa[ks], o0);
        o1 = mfma32(v1, pa[ks], o1);
      }
    }
    __syncthreads();
    bsel ^= 1;
  }

  const float invL = 1.0f / L;
  const int bb = bh >> 4, h = bh & 15;
  __bf16* aorow = ao + (size_t)(bb * S_ + q0w + lq) * 1024 + h * 64;
#pragma unroll
  for (int rr = 0; rr < 4; ++rr) {
    bf16x4 w0, w1;
#pragma unroll
    for (int j = 0; j < 4; ++j) {
      w0[j] = (__bf16)(o0[4 * rr + j] * invL);
      w1[j] = (__bf16)(o1[4 * rr + j] * invL);
    }
    *(bf16x4*)&aorow[rr * 8 + 4 * hi] = w0;
    *(bf16x4*)&aorow[32 + rr * 8 + 4 * hi] = w1;
  }
}

// ---------------- launcher ----------------
extern "C" void kernel_launch(void* const* d_in, const int* in_sizes, int n_in,
                              void* d_out, int out_size, void* d_ws, size_t ws_size,
                              hipStream_t stream) {
  (void)in_sizes; (void)n_in; (void)out_size; (void)ws_size;
  const float* x = (const float*)d_in[0];
  // d_in[1] = mask (tril ones) -> causal handled analytically
  const float* W_dkv = (const float*)d_in[2];
  const float* b_dkv = (const float*)d_in[3];
  const float* W_dq = (const float*)d_in[4];
  const float* b_dq = (const float*)d_in[5];
  const float* W_uk = (const float*)d_in[6];
  const float* b_uk = (const float*)d_in[7];
  const float* W_uv = (const float*)d_in[8];
  const float* b_uv = (const float*)d_in[9];
  const float* W_uq = (const float*)d_in[10];
  const float* b_uq = (const float*)d_in[11];
  const float* W_qr = (const float*)d_in[12];
  const float* b_qr = (const float*)d_in[13];
  const float* W_kr = (const float*)d_in[14];
  const float* b_kr = (const float*)d_in[15];
  const float* W_o = (const float*)d_in[16];
  const float* b_o = (const float*)d_in[17];
  float* out = (float*)d_out;

  char* ws = (char*)d_ws;
  size_t off = 0;
  auto take = [&](size_t nbytes) -> char* {
    char* p = ws + off;
    off += (nbytes + 255) & ~(size_t)255;
    return p;
  };
  __bf16* xb = (__bf16*)take((size_t)8192 * 1024 * 2);
  __bf16* WdT = (__bf16*)take((size_t)384 * 1024 * 2);     // [Wdq|Wdkv|Wkr|pad]^T
  __bf16* WuqT = (__bf16*)take((size_t)1536 * 128 * 2);    // [Wuq|Wqr]^T
  __bf16* WukvT = (__bf16*)take((size_t)2048 * 128 * 2);   // [Wuk|Wuv]^T
  __bf16* WoT = (__bf16*)take((size_t)1024 * 1024 * 2);
  float* bias_d = (float*)take(384 * 4);
  float* bias_uq = (float*)take(1536 * 4);
  float* bias_ukv = (float*)take(2048 * 4);
  float* ropec = (float*)take((size_t)S_ * 16 * 4);
  float* ropes = (float*)take((size_t)S_ * 16 * 4);
  __bf16* cqkvr = (__bf16*)take((size_t)8192 * 384 * 2);   // [c_q|c_kv|k_r|pad]
  __bf16* qr = (__bf16*)take((size_t)8192 * 512 * 2);      // raw q_r (pre-RoPE)
  __bf16* vv = (__bf16*)take((size_t)8192 * 1024 * 2);     // raw v
  __bf16* qt = (__bf16*)take((size_t)B_ * H_ * S_ * 96 * 2);
  __bf16* ktb = (__bf16*)take((size_t)B_ * H_ * S_ * 96 * 2);
  __bf16* vt = (__bf16*)take((size_t)B_ * H_ * 64 * S_ * 2);
  __bf16* aout = (__bf16*)take((size_t)8192 * 1024 * 2);

  // zero the padded rows of WdT (cols 288..383 of down-proj output)
  hipMemsetAsync(WdT + (size_t)288 * 1024, 0, (size_t)96 * 1024 * 2, stream);

  // fused prep: cvt_x + 8 transposes + rope tables + bias concat
  mla_prep<<<6000, 256, 0, stream>>>(x, xb, W_dq, W_dkv, W_kr, W_uq, W_qr, W_uk,
                                     W_uv, W_o, WdT, WuqT, WukvT, WoT, b_dq,
                                     b_dkv, b_kr, b_uq, b_qr, b_uk, b_uv, bias_d,
                                     bias_uq, bias_ukv, ropec, ropes);

  // down-proj: x(8192x1024) @ [Wdq|Wdkv|Wkr] -> cqkvr (8192x384)
  gemm32<0><<<dim3(3, 64), 256, 0, stream>>>(xb, 1024, WdT, 1024, bias_d,
                                             cqkvr, nullptr, 384, 1024);
  // up-proj q: c_q @ [Wuq|Wqr] -> qt (q_c, scaled) + qr (q_r raw)
  gemm32<2><<<dim3(12, 64), 256, 0, stream>>>(cqkvr, 384, WuqT, 128, bias_uq,
                                              qt, qr, 0, 128);
  // up-proj kv: c_kv @ [Wuk|Wuv] -> ktb (k_c) + vv (v raw)
  gemm32<3><<<dim3(16, 64), 256, 0, stream>>>(cqkvr + 128, 384, WukvT, 128,
                                              bias_ukv, ktb, vv, 0, 128);

  // fused glue: rope(q_r,k_r) -> qt/ktb + V -> V^T
  mla_glue<<<8192 + 2048, 256, 0, stream>>>(qr, cqkvr, ropec, ropes, qt, ktb, vv, vt);

  mla_attn<<<dim3(16, 64), 256, 0, stream>>>(qt, ktb, vt, aout);

  // final: aout(8192x1024) @ W_o + b_o -> out f32
  gemm32<1><<<dim3(8, 64), 256, 0, stream>>>(aout, 1024, WoT, 1024, b_o, out,
                                             nullptr, 1024, 1024);
}

// Round 8
// 341.286 us; speedup vs baseline: 1.2083x; 1.1378x over previous
//
#include <hip/hip_runtime.h>
#include <cstdint>
#include <cstddef>

#define S_ 2048
#define B_ 4
#define H_ 16
#define ALPHA_Q 0.14724394f  // SCALE * log2(e)

typedef __attribute__((ext_vector_type(8))) __bf16 bf16x8;
typedef __attribute__((ext_vector_type(4))) __bf16 bf16x4;
typedef __attribute__((ext_vector_type(4))) float f32x4;
typedef __attribute__((ext_vector_type(16))) float f32x16;

__device__ __forceinline__ f32x16 mfma32(bf16x8 a, bf16x8 b, f32x16 c) {
  return __builtin_amdgcn_mfma_f32_32x32x16_bf16(a, b, c, 0, 0, 0);
}

// async global->LDS, 16B per lane. LDS base must be wave-uniform (HW writes
// base + lane*16); global src is per-lane.
__device__ __forceinline__ void gll16(const void* g, void* l) {
  __builtin_amdgcn_global_load_lds(
      (__attribute__((address_space(1))) void*)(uintptr_t)g,
      (__attribute__((address_space(3))) void*)(uint32_t)(uintptr_t)l,
      16, 0, 0);
}

// v_cvt_pk_bf16_f32: packs (bf16(lo), bf16(hi)) into one dword (lo in bits 0-15)
__device__ __forceinline__ int cvtpk(float lo, float hi) {
  int r;
  asm("v_cvt_pk_bf16_f32 %0, %1, %2" : "=v"(r) : "v"(lo), "v"(hi));
  return r;
}

union PAU { int w[4]; bf16x8 v; };

// Build one 32x32x16 B-operand fragment of P^T (col=q=lane&31, k=8*hi+e)
// from 8 in-lane P values (crow order). Cross-half exchange via shfl_xor(32).
__device__ __forceinline__ bf16x8 packPA(int hi, float a0, float a1, float a2,
                                         float a3, float b0, float b1, float b2,
                                         float b3) {
  const int Ylo = cvtpk(a0, a1);
  const int Yhi = cvtpk(a2, a3);
  const int Xlo = cvtpk(b0, b1);
  const int Xhi = cvtpk(b2, b3);
  const int t0 = __shfl_xor(hi ? Ylo : Xlo, 32);
  const int t1 = __shfl_xor(hi ? Yhi : Xhi, 32);
  PAU u;
  u.w[0] = hi ? t0 : Ylo;
  u.w[1] = hi ? t1 : Yhi;
  u.w[2] = hi ? Xlo : t0;
  u.w[3] = hi ? Xhi : t1;
  return u.v;
}

// depth-5 tree max of one f32x16
__device__ __forceinline__ float tmax16(const f32x16& v) {
  float a[8];
#pragma unroll
  for (int i = 0; i < 8; ++i) a[i] = fmaxf(v[i], v[i + 8]);
#pragma unroll
  for (int s = 4; s > 0; s >>= 1)
#pragma unroll
    for (int i = 0; i < s; ++i) a[i] = fmaxf(a[i], a[i + s]);
  return a[0];
}

// ---------------- fused prep kernel ----------------
// tile-id dispatch: [0,4096) cvt_x ; [4096,5856) weight transposes ;
// [5856,5984) rope tables ; [5984,6000) bias concat.
__global__ __launch_bounds__(256) void mla_prep(
    const float* __restrict__ x, __bf16* __restrict__ xb,
    const float* __restrict__ W_dq, const float* __restrict__ W_dkv,
    const float* __restrict__ W_kr, const float* __restrict__ W_uq,
    const float* __restrict__ W_qr, const float* __restrict__ W_uk,
    const float* __restrict__ W_uv, const float* __restrict__ W_o,
    __bf16* __restrict__ WdT, __bf16* __restrict__ WuqT,
    __bf16* __restrict__ WukvT, __bf16* __restrict__ WoT,
    const float* __restrict__ b_dq, const float* __restrict__ b_dkv,
    const float* __restrict__ b_kr, const float* __restrict__ b_uq,
    const float* __restrict__ b_qr, const float* __restrict__ b_uk,
    const float* __restrict__ b_uv, float* __restrict__ bias_d,
    float* __restrict__ bias_uq, float* __restrict__ bias_ukv,
    float* __restrict__ ropec, float* __restrict__ ropes) {
  const int id = blockIdx.x;
  const int t = threadIdx.x;
  __shared__ float tile[32][33];

  if (id < 4096) {  // x f32 -> bf16
    const size_t i = ((size_t)id * 256 + t) * 8;
    float4 a = *(const float4*)&x[i];
    float4 b = *(const float4*)&x[i + 4];
    bf16x8 v;
    v[0] = (__bf16)a.x; v[1] = (__bf16)a.y; v[2] = (__bf16)a.z; v[3] = (__bf16)a.w;
    v[4] = (__bf16)b.x; v[5] = (__bf16)b.y; v[6] = (__bf16)b.z; v[7] = (__bf16)b.w;
    *(bf16x8*)&xb[i] = v;
    return;
  }
  if (id < 5856) {  // W (KxN f32) -> WT (NxK bf16)
    int rel = id - 4096;
    const float* W;
    __bf16* WT;
    int K, N, nt;
    if (rel < 128)      { W = W_dq;  WT = WdT;                      K = 1024; N = 128;  nt = 4; }
    else if (rel < 256) { W = W_dkv; WT = WdT + (size_t)128 * 1024; K = 1024; N = 128;  nt = 4;  rel -= 128; }
    else if (rel < 288) { W = W_kr;  WT = WdT + (size_t)256 * 1024; K = 1024; N = 32;   nt = 1;  rel -= 256; }
    else if (rel < 416) { W = W_uq;  WT = WuqT;                     K = 128;  N = 1024; nt = 32; rel -= 288; }
    else if (rel < 480) { W = W_qr;  WT = WuqT + (size_t)1024 * 128; K = 128; N = 512;  nt = 16; rel -= 416; }
    else if (rel < 608) { W = W_uk;  WT = WukvT;                    K = 128;  N = 1024; nt = 32; rel -= 480; }
    else if (rel < 736) { W = W_uv;  WT = WukvT + (size_t)1024 * 128; K = 128; N = 1024; nt = 32; rel -= 608; }
    else                { W = W_o;   WT = WoT;                      K = 1024; N = 1024; nt = 32; rel -= 736; }
    const int n0 = (rel % nt) * 32, k0 = (rel / nt) * 32;
    const int tx = t & 31, ty = t >> 5;
#pragma unroll
    for (int i = 0; i < 32; i += 8)
      tile[ty + i][tx] = W[(size_t)(k0 + ty + i) * N + n0 + tx];
    __syncthreads();
#pragma unroll
    for (int i = 0; i < 32; i += 8)
      WT[(size_t)(n0 + ty + i) * K + k0 + tx] = (__bf16)tile[tx][ty + i];
    return;
  }
  if (id < 5984) {  // rope tables
    const int g = (id - 5856) * 256 + t;  // < S_*16
    const int s = g >> 4, i = g & 15;
    const float inv = exp2f(-(float)i * (13.287712379549449f / 16.0f));
    const float ang = (float)s * inv;
    ropec[g] = cosf(ang);
    ropes[g] = sinf(ang);
    return;
  }
  {  // bias concat
    const int g = (id - 5984) * 256 + t;
    if (g < 384)
      bias_d[g] = (g < 128) ? b_dq[g] : (g < 256) ? b_dkv[g - 128]
                 : (g < 288) ? b_kr[g - 256] : 0.f;
    if (g < 1536) bias_uq[g] = (g < 1024) ? b_uq[g] : b_qr[g - 1024];
    if (g < 2048) bias_ukv[g] = (g < 1024) ? b_uk[g] : b_uv[g - 1024];
  }
}

// ---------------- mfma32 GEMM: C = A(MxK) * BT^T + bias ----------------
// 128x128 tile, BK=64, 4 waves 2x2 (each 64x64). LDS [slice][row][8]
// conflict-free layout. 2-barrier m97 structure.
// MODE 0: bf16 out. MODE 1: f32 out.
// MODE 2 (up-q): col<1024 -> qt[(b,h,s),d]*ALPHA_Q ; col>=1024 -> qr
// MODE 3 (up-kv): col<1024 -> ktb[(b,h,s),d] ; col>=1024 -> vv
template <int MODE>
__global__ __launch_bounds__(256) void gemm32(
    const __bf16* __restrict__ A, int lda, const __bf16* __restrict__ BT, int ldbt,
    const float* __restrict__ bias, void* __restrict__ C0, void* __restrict__ C1,
    int ldc, int K) {
  const int n0 = blockIdx.x * 128;
  const int m0 = blockIdx.y * 128;
  const int wave = threadIdx.x >> 6, lane = threadIdx.x & 63;
  const int hi = lane >> 5, lq = lane & 31;
  const int wm = (wave >> 1) * 64, wn = (wave & 1) * 64;
  __shared__ __bf16 __attribute__((aligned(16))) ldsA[8 * 128 * 8];  // 16 KB
  __shared__ __bf16 __attribute__((aligned(16))) ldsB[8 * 128 * 8];  // 16 KB

  const f32x16 fz16 = {0.f, 0.f, 0.f, 0.f, 0.f, 0.f, 0.f, 0.f,
                       0.f, 0.f, 0.f, 0.f, 0.f, 0.f, 0.f, 0.f};
  f32x16 acc00 = fz16, acc01 = fz16, acc10 = fz16, acc11 = fz16;

  for (int k0 = 0; k0 < K; k0 += 64) {
    __syncthreads();
#pragma unroll
    for (int i = 0; i < 8; ++i) {
      const int c = wave * 8 + i;
      if (c < 16) {
        const int sl = c >> 1, half = c & 1;
        gll16(&A[(size_t)(m0 + half * 64 + lane) * lda + k0 + sl * 8],
              &ldsA[(sl * 128 + half * 64) * 8]);
      } else {
        const int cc = c - 16;
        const int sl = cc >> 1, half = cc & 1;
        gll16(&BT[(size_t)(n0 + half * 64 + lane) * ldbt + k0 + sl * 8],
              &ldsB[(sl * 128 + half * 64) * 8]);
      }
    }
    __syncthreads();

#pragma unroll
    for (int ks = 0; ks < 4; ++ks) {
      const int sl = ks * 2 + hi;
      bf16x8 a0 = *(const bf16x8*)&ldsA[(sl * 128 + wm + lq) * 8];
      bf16x8 a1 = *(const bf16x8*)&ldsA[(sl * 128 + wm + 32 + lq) * 8];
      bf16x8 b0 = *(const bf16x8*)&ldsB[(sl * 128 + wn + lq) * 8];
      bf16x8 b1 = *(const bf16x8*)&ldsB[(sl * 128 + wn + 32 + lq) * 8];
      acc00 = mfma32(a0, b0, acc00);
      acc01 = mfma32(a0, b1, acc01);
      acc10 = mfma32(a1, b0, acc10);
      acc11 = mfma32(a1, b1, acc11);
    }
  }

  const f32x16* accs[2][2] = {{&acc00, &acc01}, {&acc10, &acc11}};
#pragma unroll
  for (int ni = 0; ni < 2; ++ni) {
    const int col = n0 + wn + ni * 32 + lq;
    const float bv = bias[col];
#pragma unroll
    for (int mi = 0; mi < 2; ++mi) {
      const f32x16& ac = *accs[mi][ni];
#pragma unroll
      for (int r = 0; r < 16; ++r) {
        const int row = m0 + wm + mi * 32 + (r & 3) + 8 * (r >> 2) + 4 * hi;
        const float v = ac[r] + bv;
        if (MODE == 0) {
          ((__bf16*)C0)[(size_t)row * ldc + col] = (__bf16)v;
        } else if (MODE == 1) {
          ((float*)C0)[(size_t)row * ldc + col] = v;
        } else {
          const int b = row >> 11, s = row & 2047;
          if (col < 1024) {
            const int h = col >> 6, d = col & 63;
            const size_t o = ((size_t)(b * H_ + h) * S_ + s) * 96 + d;
            if (MODE == 2)
              ((__bf16*)C0)[o] = (__bf16)(v * ALPHA_Q);
            else
              ((__bf16*)C0)[o] = (__bf16)v;
          } else {
            if (MODE == 2)
              ((__bf16*)C1)[(size_t)row * 512 + col - 1024] = (__bf16)v;
            else
              ((__bf16*)C1)[(size_t)row * 1024 + col - 1024] = (__bf16)v;
          }
        }
      }
    }
  }
}

// ---------------- fused glue: RoPE(q_r,k_r) + V transpose ----------------
// blockIdx.x < 8192: rope path ; else vtrans path (bid-8192 -> (s-tile, bh)).
__global__ __launch_bounds__(256) void mla_glue(
    const __bf16* __restrict__ qr, const __bf16* __restrict__ cqkvr,
    const float* __restrict__ ropec, const float* __restrict__ ropes,
    __bf16* __restrict__ qt, __bf16* __restrict__ ktb,
    const __bf16* __restrict__ vv, __bf16* __restrict__ vt) {
  __shared__ __bf16 __attribute__((aligned(16))) tile[64][72];
  const int t = threadIdx.x;
  if (blockIdx.x < 8192) {
    const int gid = blockIdx.x * 256 + t;
    const int bs = gid >> 8;
    const int h = (gid >> 4) & 15;
    const int i = gid & 15;
    const int b = bs >> 11, s = bs & 2047;
    const float c = ropec[s * 16 + i], sn = ropes[s * 16 + i];
    const size_t o = ((size_t)(b * H_ + h) * S_ + s) * 96 + 64 + 2 * i;
    {
      const float r = (float)qr[(size_t)bs * 512 + h * 32 + 2 * i];
      const float im = (float)qr[(size_t)bs * 512 + h * 32 + 2 * i + 1];
      qt[o] = (__bf16)((r * c - im * sn) * ALPHA_Q);
      qt[o + 1] = (__bf16)((r * sn + im * c) * ALPHA_Q);
    }
    {
      const float r = (float)cqkvr[(size_t)bs * 384 + 256 + 2 * i];
      const float im = (float)cqkvr[(size_t)bs * 384 + 256 + 2 * i + 1];
      ktb[o] = (__bf16)(r * c - im * sn);
      ktb[o + 1] = (__bf16)(r * sn + im * c);
    }
    return;
  }
  const int bid = blockIdx.x - 8192;
  const int s0 = (bid & 31) * 64;
  const int bh = bid >> 5;
  const int b = bh >> 4, h = bh & 15;
  {
    const int r = t >> 2, c0 = (t & 3) * 16;
    const size_t src = (size_t)(b * S_ + s0 + r) * 1024 + h * 64 + c0;
    bf16x8 u0 = *(const bf16x8*)&vv[src];
    bf16x8 u1 = *(const bf16x8*)&vv[src + 8];
    *(bf16x8*)&tile[r][c0] = u0;
    *(bf16x8*)&tile[r][c0 + 8] = u1;
  }
  __syncthreads();
  {
    const int d = t >> 2, sc0 = (t & 3) * 16;
    bf16x8 w0, w1;
#pragma unroll
    for (int e = 0; e < 8; ++e) {
      w0[e] = tile[sc0 + e][d];
      w1[e] = tile[sc0 + 8 + e][d];
    }
    const size_t dst = ((size_t)bh * 64 + d) * S_ + s0 + sc0;
    *(bf16x8*)&vt[dst] = w0;
    *(bf16x8*)&vt[dst + 8] = w1;
  }
}

// ---------------- causal flash attention (32x32 MFMA, work-paired) ----------
// grid (8, B*H). Block j processes q-blocks j AND 15-j sequentially: total
// staged tiles = (2j+2)+(2(15-j)+2) = 34 for EVERY block -> uniform per-CU
// work regardless of block->CU mapping (fixes the x-period-16 imbalance that
// pinned same-qblk blocks onto the same CU).
__global__ __launch_bounds__(256, 3) void mla_attn(const __bf16* __restrict__ qt,
                                                   const __bf16* __restrict__ kt,
                                                   const __bf16* __restrict__ vt,
                                                   __bf16* __restrict__ ao) {
  const int j = blockIdx.x;  // 0..7
  const int bh = blockIdx.y;
  const int wave = threadIdx.x >> 6, lane = threadIdx.x & 63;
  const int hi = lane >> 5, lq = lane & 31;
  const __bf16* Q = qt + (size_t)bh * S_ * 96;
  const __bf16* Kp = kt + (size_t)bh * S_ * 96;
  const __bf16* Vp = vt + (size_t)bh * 64 * S_;
  const int bb = bh >> 4, h = bh & 15;

  __shared__ __bf16 __attribute__((aligned(16))) kbuf[2][12 * 512];
  __shared__ __bf16 __attribute__((aligned(16))) vbuf[2][8 * 512];

  const f32x16 fz16 = {0.f, 0.f, 0.f, 0.f, 0.f, 0.f, 0.f, 0.f,
                       0.f, 0.f, 0.f, 0.f, 0.f, 0.f, 0.f, 0.f};

  auto stage = [&](int t, int bsel) {
    const int kv0 = t * 64;
#pragma unroll
    for (int i = 0; i < 5; ++i) {
      const int c = wave + 4 * i;
      if (c < 12)
        gll16(&Kp[(size_t)(kv0 + lane) * 96 + c * 8], &kbuf[bsel][c * 512]);
      else
        gll16(&Vp[(size_t)lane * S_ + kv0 + (c - 12) * 8], &vbuf[bsel][(c - 12) * 512]);
    }
  };

  for (int pass = 0; pass < 2; ++pass) {
    const int qblk = pass ? (15 - j) : j;
    const int q0w = qblk * 128 + wave * 32;

    bf16x8 qf[6];
#pragma unroll
    for (int kd = 0; kd < 6; ++kd)
      qf[kd] = *(const bf16x8*)&Q[(size_t)(q0w + lq) * 96 + kd * 16 + hi * 8];

    f32x16 o0 = fz16, o1 = fz16;
    float m = -3.0e38f, L = 0.f;

    const int tEnd = (q0w + 31) >> 6;  // last tile this wave computes
    const int tMax = qblk * 2 + 1;     // last tile the block stages

    stage(0, 0);
    __syncthreads();

    int bsel = 0;
    for (int t = 0; t <= tMax; ++t) {
      if (t < tMax) stage(t + 1, bsel ^ 1);
      if (t <= tEnd) {
        f32x16 s0 = fz16, s1 = fz16;
#pragma unroll
        for (int kd = 0; kd < 6; ++kd) {
          const int sl = kd * 2 + hi;
          bf16x8 a0 = *(const bf16x8*)&kbuf[bsel][(sl * 64 + lq) * 8];
          bf16x8 a1 = *(const bf16x8*)&kbuf[bsel][(sl * 64 + 32 + lq) * 8];
          s0 = mfma32(a0, qf[kd], s0);
          s1 = mfma32(a1, qf[kd], s1);
        }
        if (t == tEnd) {
          const int qg = q0w + lq;
          const int kvb = t * 64 + 4 * hi;
#pragma unroll
          for (int r = 0; r < 16; ++r) {
            const int crow = (r & 3) + 8 * (r >> 2);
            if (kvb + crow > qg) s0[r] = -3.0e38f;
            if (kvb + 32 + crow > qg) s1[r] = -3.0e38f;
          }
        }
        float tm = fmaxf(tmax16(s0), tmax16(s1));
        tm = fmaxf(tm, __shfl_xor(tm, 32));
        // defer-max (T13): rescale only when max grew by > 8 (log2 domain)
        if (!__all(tm <= m + 8.0f)) {
          const float mnew = fmaxf(m, tm);
          const float sc = exp2f(m - mnew);
          m = mnew;
          L *= sc;
          o0 *= sc;
          o1 *= sc;
        }
        float p0[16], p1[16];
#pragma unroll
        for (int r = 0; r < 16; ++r) {
          p0[r] = exp2f(s0[r] - m);
          p1[r] = exp2f(s1[r] - m);
        }
        float a[16];
#pragma unroll
        for (int r = 0; r < 16; ++r) a[r] = p0[r] + p1[r];
#pragma unroll
        for (int s = 8; s > 0; s >>= 1)
#pragma unroll
          for (int i = 0; i < s; ++i) a[i] += a[i + s];
        float ps = a[0];
        ps += __shfl_xor(ps, 32);
        L += ps;
        bf16x8 pa[4];
        pa[0] = packPA(hi, p0[0], p0[1], p0[2], p0[3], p0[4], p0[5], p0[6], p0[7]);
        pa[1] = packPA(hi, p0[8], p0[9], p0[10], p0[11], p0[12], p0[13], p0[14], p0[15]);
        pa[2] = packPA(hi, p1[0], p1[1], p1[2], p1[3], p1[4], p1[5], p1[6], p1[7]);
        pa[3] = packPA(hi, p1[8], p1[9], p1[10], p1[11], p1[12], p1[13], p1[14], p1[15]);
#pragma unroll
        for (int ks = 0; ks < 4; ++ks) {
          const int sl = ks * 2 + hi;
          bf16x8 v0 = *(const bf16x8*)&vbuf[bsel][(sl * 64 + lq) * 8];
          bf16x8 v1 = *(const bf16x8*)&vbuf[bsel][(sl * 64 + 32 + lq) * 8];
          o0 = mfma32(v0, pa[ks], o0);
          o1 = mfma32(v1, pa[ks], o1);
        }
      }
      __syncthreads();  // stage(t+1) complete + LDS reads of bsel done
      bsel ^= 1;
    }

    const float invL = 1.0f / L;
    __bf16* aorow = ao + (size_t)(bb * S_ + q0w + lq) * 1024 + h * 64;
#pragma unroll
    for (int rr = 0; rr < 4; ++rr) {
      bf16x4 w0, w1;
#pragma unroll
      for (int jj = 0; jj < 4; ++jj) {
        w0[jj] = (__bf16)(o0[4 * rr + jj] * invL);
        w1[jj] = (__bf16)(o1[4 * rr + jj] * invL);
      }
      *(bf16x4*)&aorow[rr * 8 + 4 * hi] = w0;
      *(bf16x4*)&aorow[32 + rr * 8 + 4 * hi] = w1;
    }
  }
}

// ---------------- launcher ----------------
extern "C" void kernel_launch(void* const* d_in, const int* in_sizes, int n_in,
                              void* d_out, int out_size, void* d_ws, size_t ws_size,
                              hipStream_t stream) {
  (void)in_sizes; (void)n_in; (void)out_size; (void)ws_size;
  const float* x = (const float*)d_in[0];
  // d_in[1] = mask (tril ones) -> causal handled analytically
  const float* W_dkv = (const float*)d_in[2];
  const float* b_dkv = (const float*)d_in[3];
  const float* W_dq = (const float*)d_in[4];
  const float* b_dq = (const float*)d_in[5];
  const float* W_uk = (const float*)d_in[6];
  const float* b_uk = (const float*)d_in[7];
  const float* W_uv = (const float*)d_in[8];
  const float* b_uv = (const float*)d_in[9];
  const float* W_uq = (const float*)d_in[10];
  const float* b_uq = (const float*)d_in[11];
  const float* W_qr = (const float*)d_in[12];
  const float* b_qr = (const float*)d_in[13];
  const float* W_kr = (const float*)d_in[14];
  const float* b_kr = (const float*)d_in[15];
  const float* W_o = (const float*)d_in[16];
  const float* b_o = (const float*)d_in[17];
  float* out = (float*)d_out;

  char* ws = (char*)d_ws;
  size_t off = 0;
  auto take = [&](size_t nbytes) -> char* {
    char* p = ws + off;
    off += (nbytes + 255) & ~(size_t)255;
    return p;
  };
  __bf16* xb = (__bf16*)take((size_t)8192 * 1024 * 2);
  __bf16* WdT = (__bf16*)take((size_t)384 * 1024 * 2);     // [Wdq|Wdkv|Wkr|pad]^T
  __bf16* WuqT = (__bf16*)take((size_t)1536 * 128 * 2);    // [Wuq|Wqr]^T
  __bf16* WukvT = (__bf16*)take((size_t)2048 * 128 * 2);   // [Wuk|Wuv]^T
  __bf16* WoT = (__bf16*)take((size_t)1024 * 1024 * 2);
  float* bias_d = (float*)take(384 * 4);
  float* bias_uq = (float*)take(1536 * 4);
  float* bias_ukv = (float*)take(2048 * 4);
  float* ropec = (float*)take((size_t)S_ * 16 * 4);
  float* ropes = (float*)take((size_t)S_ * 16 * 4);
  __bf16* cqkvr = (__bf16*)take((size_t)8192 * 384 * 2);   // [c_q|c_kv|k_r|pad]
  __bf16* qr = (__bf16*)take((size_t)8192 * 512 * 2);      // raw q_r (pre-RoPE)
  __bf16* vv = (__bf16*)take((size_t)8192 * 1024 * 2);     // raw v
  __bf16* qt = (__bf16*)take((size_t)B_ * H_ * S_ * 96 * 2);
  __bf16* ktb = (__bf16*)take((size_t)B_ * H_ * S_ * 96 * 2);
  __bf16* vt = (__bf16*)take((size_t)B_ * H_ * 64 * S_ * 2);
  __bf16* aout = (__bf16*)take((size_t)8192 * 1024 * 2);

  // zero the padded rows of WdT (cols 288..383 of down-proj output)
  hipMemsetAsync(WdT + (size_t)288 * 1024, 0, (size_t)96 * 1024 * 2, stream);

  // fused prep: cvt_x + 8 transposes + rope tables + bias concat
  mla_prep<<<6000, 256, 0, stream>>>(x, xb, W_dq, W_dkv, W_kr, W_uq, W_qr, W_uk,
                                     W_uv, W_o, WdT, WuqT, WukvT, WoT, b_dq,
                                     b_dkv, b_kr, b_uq, b_qr, b_uk, b_uv, bias_d,
                                     bias_uq, bias_ukv, ropec, ropes);

  // down-proj: x(8192x1024) @ [Wdq|Wdkv|Wkr] -> cqkvr (8192x384)
  gemm32<0><<<dim3(3, 64), 256, 0, stream>>>(xb, 1024, WdT, 1024, bias_d,
                                             cqkvr, nullptr, 384, 1024);
  // up-proj q: c_q @ [Wuq|Wqr] -> qt (q_c, scaled) + qr (q_r raw)
  gemm32<2><<<dim3(12, 64), 256, 0, stream>>>(cqkvr, 384, WuqT, 128, bias_uq,
                                              qt, qr, 0, 128);
  // up-proj kv: c_kv @ [Wuk|Wuv] -> ktb (k_c) + vv (v raw)
  gemm32<3><<<dim3(16, 64), 256, 0, stream>>>(cqkvr + 128, 384, WukvT, 128,
                                              bias_ukv, ktb, vv, 0, 128);

  // fused glue: rope(q_r,k_r) -> qt/ktb + V -> V^T
  mla_glue<<<8192 + 2048, 256, 0, stream>>>(qr, cqkvr, ropec, ropes, qt, ktb, vv, vt);

  mla_attn<<<dim3(8, 64), 256, 0, stream>>>(qt, ktb, vt, aout);

  // final: aout(8192x1024) @ W_o + b_o -> out f32
  gemm32<1><<<dim3(8, 64), 256, 0, stream>>>(aout, 1024, WoT, 1024, b_o, out,
                                             nullptr, 1024, 1024);
}

// Round 9
// 339.855 us; speedup vs baseline: 1.2134x; 1.0042x over previous
//
#include <hip/hip_runtime.h>
#include <cstdint>
#include <cstddef>

#define S_ 2048
#define B_ 4
#define H_ 16
#define ALPHA_Q 0.14724394f  // SCALE * log2(e)

typedef __attribute__((ext_vector_type(8))) __bf16 bf16x8;
typedef __attribute__((ext_vector_type(4))) __bf16 bf16x4;
typedef __attribute__((ext_vector_type(4))) float f32x4;
typedef __attribute__((ext_vector_type(16))) float f32x16;

__device__ __forceinline__ f32x16 mfma32(bf16x8 a, bf16x8 b, f32x16 c) {
  return __builtin_amdgcn_mfma_f32_32x32x16_bf16(a, b, c, 0, 0, 0);
}

// async global->LDS, 16B per lane. LDS base must be wave-uniform (HW writes
// base + lane*16); global src is per-lane.
__device__ __forceinline__ void gll16(const void* g, void* l) {
  __builtin_amdgcn_global_load_lds(
      (__attribute__((address_space(1))) void*)(uintptr_t)g,
      (__attribute__((address_space(3))) void*)(uint32_t)(uintptr_t)l,
      16, 0, 0);
}

// v_cvt_pk_bf16_f32: packs (bf16(lo), bf16(hi)) into one dword (lo in bits 0-15)
__device__ __forceinline__ int cvtpk(float lo, float hi) {
  int r;
  asm("v_cvt_pk_bf16_f32 %0, %1, %2" : "=v"(r) : "v"(lo), "v"(hi));
  return r;
}

union PAU { int w[4]; bf16x8 v; };

// Build one 32x32x16 B-operand fragment of P^T (col=q=lane&31, k=8*hi+e)
// from 8 in-lane P values (crow order). Cross-half exchange via shfl_xor(32).
__device__ __forceinline__ bf16x8 packPA(int hi, float a0, float a1, float a2,
                                         float a3, float b0, float b1, float b2,
                                         float b3) {
  const int Ylo = cvtpk(a0, a1);
  const int Yhi = cvtpk(a2, a3);
  const int Xlo = cvtpk(b0, b1);
  const int Xhi = cvtpk(b2, b3);
  const int t0 = __shfl_xor(hi ? Ylo : Xlo, 32);
  const int t1 = __shfl_xor(hi ? Yhi : Xhi, 32);
  PAU u;
  u.w[0] = hi ? t0 : Ylo;
  u.w[1] = hi ? t1 : Yhi;
  u.w[2] = hi ? Xlo : t0;
  u.w[3] = hi ? Xhi : t1;
  return u.v;
}

// depth-5 tree max of one f32x16
__device__ __forceinline__ float tmax16(const f32x16& v) {
  float a[8];
#pragma unroll
  for (int i = 0; i < 8; ++i) a[i] = fmaxf(v[i], v[i + 8]);
#pragma unroll
  for (int s = 4; s > 0; s >>= 1)
#pragma unroll
    for (int i = 0; i < s; ++i) a[i] = fmaxf(a[i], a[i + s]);
  return a[0];
}

// ---------------- fused prep kernel ----------------
// tile-id dispatch: [0,4096) cvt_x ; [4096,5856) weight transposes ;
// [5856,5984) rope tables ; [5984,6000) bias concat.
__global__ __launch_bounds__(256) void mla_prep(
    const float* __restrict__ x, __bf16* __restrict__ xb,
    const float* __restrict__ W_dq, const float* __restrict__ W_dkv,
    const float* __restrict__ W_kr, const float* __restrict__ W_uq,
    const float* __restrict__ W_qr, const float* __restrict__ W_uk,
    const float* __restrict__ W_uv, const float* __restrict__ W_o,
    __bf16* __restrict__ WdT, __bf16* __restrict__ WuqT,
    __bf16* __restrict__ WukvT, __bf16* __restrict__ WoT,
    const float* __restrict__ b_dq, const float* __restrict__ b_dkv,
    const float* __restrict__ b_kr, const float* __restrict__ b_uq,
    const float* __restrict__ b_qr, const float* __restrict__ b_uk,
    const float* __restrict__ b_uv, float* __restrict__ bias_d,
    float* __restrict__ bias_uq, float* __restrict__ bias_ukv,
    float* __restrict__ ropec, float* __restrict__ ropes) {
  const int id = blockIdx.x;
  const int t = threadIdx.x;
  __shared__ float tile[32][33];

  if (id < 4096) {  // x f32 -> bf16
    const size_t i = ((size_t)id * 256 + t) * 8;
    float4 a = *(const float4*)&x[i];
    float4 b = *(const float4*)&x[i + 4];
    bf16x8 v;
    v[0] = (__bf16)a.x; v[1] = (__bf16)a.y; v[2] = (__bf16)a.z; v[3] = (__bf16)a.w;
    v[4] = (__bf16)b.x; v[5] = (__bf16)b.y; v[6] = (__bf16)b.z; v[7] = (__bf16)b.w;
    *(bf16x8*)&xb[i] = v;
    return;
  }
  if (id < 5856) {  // W (KxN f32) -> WT (NxK bf16)
    int rel = id - 4096;
    const float* W;
    __bf16* WT;
    int K, N, nt;
    if (rel < 128)      { W = W_dq;  WT = WdT;                      K = 1024; N = 128;  nt = 4; }
    else if (rel < 256) { W = W_dkv; WT = WdT + (size_t)128 * 1024; K = 1024; N = 128;  nt = 4;  rel -= 128; }
    else if (rel < 288) { W = W_kr;  WT = WdT + (size_t)256 * 1024; K = 1024; N = 32;   nt = 1;  rel -= 256; }
    else if (rel < 416) { W = W_uq;  WT = WuqT;                     K = 128;  N = 1024; nt = 32; rel -= 288; }
    else if (rel < 480) { W = W_qr;  WT = WuqT + (size_t)1024 * 128; K = 128; N = 512;  nt = 16; rel -= 416; }
    else if (rel < 608) { W = W_uk;  WT = WukvT;                    K = 128;  N = 1024; nt = 32; rel -= 480; }
    else if (rel < 736) { W = W_uv;  WT = WukvT + (size_t)1024 * 128; K = 128; N = 1024; nt = 32; rel -= 608; }
    else                { W = W_o;   WT = WoT;                      K = 1024; N = 1024; nt = 32; rel -= 736; }
    const int n0 = (rel % nt) * 32, k0 = (rel / nt) * 32;
    const int tx = t & 31, ty = t >> 5;
#pragma unroll
    for (int i = 0; i < 32; i += 8)
      tile[ty + i][tx] = W[(size_t)(k0 + ty + i) * N + n0 + tx];
    __syncthreads();
#pragma unroll
    for (int i = 0; i < 32; i += 8)
      WT[(size_t)(n0 + ty + i) * K + k0 + tx] = (__bf16)tile[tx][ty + i];
    return;
  }
  if (id < 5984) {  // rope tables
    const int g = (id - 5856) * 256 + t;  // < S_*16
    const int s = g >> 4, i = g & 15;
    const float inv = exp2f(-(float)i * (13.287712379549449f / 16.0f));
    const float ang = (float)s * inv;
    ropec[g] = cosf(ang);
    ropes[g] = sinf(ang);
    return;
  }
  {  // bias concat
    const int g = (id - 5984) * 256 + t;
    if (g < 384)
      bias_d[g] = (g < 128) ? b_dq[g] : (g < 256) ? b_dkv[g - 128]
                 : (g < 288) ? b_kr[g - 256] : 0.f;
    if (g < 1536) bias_uq[g] = (g < 1024) ? b_uq[g] : b_qr[g - 1024];
    if (g < 2048) bias_ukv[g] = (g < 1024) ? b_uk[g] : b_uv[g - 1024];
  }
}

// ---------------- mfma32 GEMM: C = A(MxK) * BT^T + bias ----------------
// 128x128 tile, BK=64, 4 waves 2x2 (each 64x64). MODE 0: bf16 out. 1: f32 out.
template <int MODE>
__global__ __launch_bounds__(256) void gemm32(
    const __bf16* __restrict__ A, int lda, const __bf16* __restrict__ BT, int ldbt,
    const float* __restrict__ bias, void* __restrict__ C0, int ldc, int K) {
  const int n0 = blockIdx.x * 128;
  const int m0 = blockIdx.y * 128;
  const int wave = threadIdx.x >> 6, lane = threadIdx.x & 63;
  const int hi = lane >> 5, lq = lane & 31;
  const int wm = (wave >> 1) * 64, wn = (wave & 1) * 64;
  __shared__ __bf16 __attribute__((aligned(16))) ldsA[8 * 128 * 8];  // 16 KB
  __shared__ __bf16 __attribute__((aligned(16))) ldsB[8 * 128 * 8];  // 16 KB

  const f32x16 fz16 = {0.f, 0.f, 0.f, 0.f, 0.f, 0.f, 0.f, 0.f,
                       0.f, 0.f, 0.f, 0.f, 0.f, 0.f, 0.f, 0.f};
  f32x16 acc00 = fz16, acc01 = fz16, acc10 = fz16, acc11 = fz16;

  for (int k0 = 0; k0 < K; k0 += 64) {
    __syncthreads();
#pragma unroll
    for (int i = 0; i < 8; ++i) {
      const int c = wave * 8 + i;
      if (c < 16) {
        const int sl = c >> 1, half = c & 1;
        gll16(&A[(size_t)(m0 + half * 64 + lane) * lda + k0 + sl * 8],
              &ldsA[(sl * 128 + half * 64) * 8]);
      } else {
        const int cc = c - 16;
        const int sl = cc >> 1, half = cc & 1;
        gll16(&BT[(size_t)(n0 + half * 64 + lane) * ldbt + k0 + sl * 8],
              &ldsB[(sl * 128 + half * 64) * 8]);
      }
    }
    __syncthreads();

#pragma unroll
    for (int ks = 0; ks < 4; ++ks) {
      const int sl = ks * 2 + hi;
      bf16x8 a0 = *(const bf16x8*)&ldsA[(sl * 128 + wm + lq) * 8];
      bf16x8 a1 = *(const bf16x8*)&ldsA[(sl * 128 + wm + 32 + lq) * 8];
      bf16x8 b0 = *(const bf16x8*)&ldsB[(sl * 128 + wn + lq) * 8];
      bf16x8 b1 = *(const bf16x8*)&ldsB[(sl * 128 + wn + 32 + lq) * 8];
      acc00 = mfma32(a0, b0, acc00);
      acc01 = mfma32(a0, b1, acc01);
      acc10 = mfma32(a1, b0, acc10);
      acc11 = mfma32(a1, b1, acc11);
    }
  }

  const f32x16* accs[2][2] = {{&acc00, &acc01}, {&acc10, &acc11}};
#pragma unroll
  for (int ni = 0; ni < 2; ++ni) {
    const int col = n0 + wn + ni * 32 + lq;
    const float bv = bias[col];
#pragma unroll
    for (int mi = 0; mi < 2; ++mi) {
      const f32x16& ac = *accs[mi][ni];
#pragma unroll
      for (int r = 0; r < 16; ++r) {
        const int row = m0 + wm + mi * 32 + (r & 3) + 8 * (r >> 2) + 4 * hi;
        const float v = ac[r] + bv;
        if (MODE == 0)
          ((__bf16*)C0)[(size_t)row * ldc + col] = (__bf16)v;
        else
          ((float*)C0)[(size_t)row * ldc + col] = v;
      }
    }
  }
}

// ---------------- merged up-proj GEMM (block-diagonal N) ----------------
// blockIdx.x < 12: up-q (c_q @ [Wuq|Wqr] -> qt scaled / qr raw)
// blockIdx.x >= 12: up-kv (c_kv @ [Wuk|Wuv] -> ktb / vv)
__global__ __launch_bounds__(256) void gemm32up(
    const __bf16* __restrict__ cqkvr, const __bf16* __restrict__ WuqT,
    const __bf16* __restrict__ WukvT, const float* __restrict__ bias_uq,
    const float* __restrict__ bias_ukv, __bf16* __restrict__ qt,
    __bf16* __restrict__ qr, __bf16* __restrict__ ktb, __bf16* __restrict__ vv) {
  const bool isQ = blockIdx.x < 12;
  const int n0 = (isQ ? blockIdx.x : (blockIdx.x - 12)) * 128;
  const __bf16* A = cqkvr + (isQ ? 0 : 128);
  const __bf16* BT = isQ ? WuqT : WukvT;
  const float* bias = isQ ? bias_uq : bias_ukv;
  const int m0 = blockIdx.y * 128;
  const int wave = threadIdx.x >> 6, lane = threadIdx.x & 63;
  const int hi = lane >> 5, lq = lane & 31;
  const int wm = (wave >> 1) * 64, wn = (wave & 1) * 64;
  __shared__ __bf16 __attribute__((aligned(16))) ldsA[8 * 128 * 8];
  __shared__ __bf16 __attribute__((aligned(16))) ldsB[8 * 128 * 8];

  const f32x16 fz16 = {0.f, 0.f, 0.f, 0.f, 0.f, 0.f, 0.f, 0.f,
                       0.f, 0.f, 0.f, 0.f, 0.f, 0.f, 0.f, 0.f};
  f32x16 acc00 = fz16, acc01 = fz16, acc10 = fz16, acc11 = fz16;

  for (int k0 = 0; k0 < 128; k0 += 64) {
    __syncthreads();
#pragma unroll
    for (int i = 0; i < 8; ++i) {
      const int c = wave * 8 + i;
      if (c < 16) {
        const int sl = c >> 1, half = c & 1;
        gll16(&A[(size_t)(m0 + half * 64 + lane) * 384 + k0 + sl * 8],
              &ldsA[(sl * 128 + half * 64) * 8]);
      } else {
        const int cc = c - 16;
        const int sl = cc >> 1, half = cc & 1;
        gll16(&BT[(size_t)(n0 + half * 64 + lane) * 128 + k0 + sl * 8],
              &ldsB[(sl * 128 + half * 64) * 8]);
      }
    }
    __syncthreads();

#pragma unroll
    for (int ks = 0; ks < 4; ++ks) {
      const int sl = ks * 2 + hi;
      bf16x8 a0 = *(const bf16x8*)&ldsA[(sl * 128 + wm + lq) * 8];
      bf16x8 a1 = *(const bf16x8*)&ldsA[(sl * 128 + wm + 32 + lq) * 8];
      bf16x8 b0 = *(const bf16x8*)&ldsB[(sl * 128 + wn + lq) * 8];
      bf16x8 b1 = *(const bf16x8*)&ldsB[(sl * 128 + wn + 32 + lq) * 8];
      acc00 = mfma32(a0, b0, acc00);
      acc01 = mfma32(a0, b1, acc01);
      acc10 = mfma32(a1, b0, acc10);
      acc11 = mfma32(a1, b1, acc11);
    }
  }

  const f32x16* accs[2][2] = {{&acc00, &acc01}, {&acc10, &acc11}};
#pragma unroll
  for (int ni = 0; ni < 2; ++ni) {
    const int col = n0 + wn + ni * 32 + lq;
    const float bv = bias[col];
#pragma unroll
    for (int mi = 0; mi < 2; ++mi) {
      const f32x16& ac = *accs[mi][ni];
#pragma unroll
      for (int r = 0; r < 16; ++r) {
        const int row = m0 + wm + mi * 32 + (r & 3) + 8 * (r >> 2) + 4 * hi;
        const float v = ac[r] + bv;
        const int b = row >> 11, s = row & 2047;
        if (col < 1024) {
          const int h = col >> 6, d = col & 63;
          const size_t o = ((size_t)(b * H_ + h) * S_ + s) * 96 + d;
          if (isQ)
            qt[o] = (__bf16)(v * ALPHA_Q);
          else
            ktb[o] = (__bf16)v;
        } else {
          if (isQ)
            qr[(size_t)row * 512 + col - 1024] = (__bf16)v;
          else
            vv[(size_t)row * 1024 + col - 1024] = (__bf16)v;
        }
      }
    }
  }
}

// ---------------- fused glue: RoPE(q_r,k_r) + V transpose ----------------
__global__ __launch_bounds__(256) void mla_glue(
    const __bf16* __restrict__ qr, const __bf16* __restrict__ cqkvr,
    const float* __restrict__ ropec, const float* __restrict__ ropes,
    __bf16* __restrict__ qt, __bf16* __restrict__ ktb,
    const __bf16* __restrict__ vv, __bf16* __restrict__ vt) {
  __shared__ __bf16 __attribute__((aligned(16))) tile[64][72];
  const int t = threadIdx.x;
  if (blockIdx.x < 8192) {
    const int gid = blockIdx.x * 256 + t;
    const int bs = gid >> 8;
    const int h = (gid >> 4) & 15;
    const int i = gid & 15;
    const int b = bs >> 11, s = bs & 2047;
    const float c = ropec[s * 16 + i], sn = ropes[s * 16 + i];
    const size_t o = ((size_t)(b * H_ + h) * S_ + s) * 96 + 64 + 2 * i;
    {
      const float r = (float)qr[(size_t)bs * 512 + h * 32 + 2 * i];
      const float im = (float)qr[(size_t)bs * 512 + h * 32 + 2 * i + 1];
      qt[o] = (__bf16)((r * c - im * sn) * ALPHA_Q);
      qt[o + 1] = (__bf16)((r * sn + im * c) * ALPHA_Q);
    }
    {
      const float r = (float)cqkvr[(size_t)bs * 384 + 256 + 2 * i];
      const float im = (float)cqkvr[(size_t)bs * 384 + 256 + 2 * i + 1];
      ktb[o] = (__bf16)(r * c - im * sn);
      ktb[o + 1] = (__bf16)(r * sn + im * c);
    }
    return;
  }
  const int bid = blockIdx.x - 8192;
  const int s0 = (bid & 31) * 64;
  const int bh = bid >> 5;
  const int b = bh >> 4, h = bh & 15;
  {
    const int r = t >> 2, c0 = (t & 3) * 16;
    const size_t src = (size_t)(b * S_ + s0 + r) * 1024 + h * 64 + c0;
    bf16x8 u0 = *(const bf16x8*)&vv[src];
    bf16x8 u1 = *(const bf16x8*)&vv[src + 8];
    *(bf16x8*)&tile[r][c0] = u0;
    *(bf16x8*)&tile[r][c0 + 8] = u1;
  }
  __syncthreads();
  {
    const int d = t >> 2, sc0 = (t & 3) * 16;
    bf16x8 w0, w1;
#pragma unroll
    for (int e = 0; e < 8; ++e) {
      w0[e] = tile[sc0 + e][d];
      w1[e] = tile[sc0 + 8 + e][d];
    }
    const size_t dst = ((size_t)bh * 64 + d) * S_ + s0 + sc0;
    *(bf16x8*)&vt[dst] = w0;
    *(bf16x8*)&vt[dst + 8] = w1;
  }
}

// ---------------- causal flash attention (32x32 MFMA, work-paired) ----------
// grid (B*H=64, 8): bh = blockIdx.x so linear bid % 8 = bh % 8 -> all 8
// j-blocks of one bh land on ONE XCD (T1: shared 640KB KV stays in that L2).
// Block j processes q-blocks j and 15-j: uniform 34 staged tiles per block.
// L is accumulated on the MFMA pipe via an all-ones A fragment (only reg 0
// of Lacc is ever read/rescaled).
__global__ __launch_bounds__(256, 3) void mla_attn(const __bf16* __restrict__ qt,
                                                   const __bf16* __restrict__ kt,
                                                   const __bf16* __restrict__ vt,
                                                   __bf16* __restrict__ ao) {
  const int bh = blockIdx.x;
  const int j = blockIdx.y;  // 0..7
  const int wave = threadIdx.x >> 6, lane = threadIdx.x & 63;
  const int hi = lane >> 5, lq = lane & 31;
  const __bf16* Q = qt + (size_t)bh * S_ * 96;
  const __bf16* Kp = kt + (size_t)bh * S_ * 96;
  const __bf16* Vp = vt + (size_t)bh * 64 * S_;
  const int bb = bh >> 4, h = bh & 15;

  __shared__ __bf16 __attribute__((aligned(16))) kbuf[2][12 * 512];
  __shared__ __bf16 __attribute__((aligned(16))) vbuf[2][8 * 512];

  const f32x16 fz16 = {0.f, 0.f, 0.f, 0.f, 0.f, 0.f, 0.f, 0.f,
                       0.f, 0.f, 0.f, 0.f, 0.f, 0.f, 0.f, 0.f};
  bf16x8 onesA;
#pragma unroll
  for (int e = 0; e < 8; ++e) onesA[e] = (__bf16)1.0f;

  for (int pass = 0; pass < 2; ++pass) {
    const int qblk = pass ? (15 - j) : j;
    const int q0w = qblk * 128 + wave * 32;

    bf16x8 qf[6];
#pragma unroll
    for (int kd = 0; kd < 6; ++kd)
      qf[kd] = *(const bf16x8*)&Q[(size_t)(q0w + lq) * 96 + kd * 16 + hi * 8];

    f32x16 o0 = fz16, o1 = fz16, Lacc = fz16;
    float m = -3.0e38f;

    const int tEnd = (q0w + 31) >> 6;  // last tile this wave computes
    const int tMax = qblk * 2 + 1;     // last tile the block stages

    // per-wave staging base pointers (advance by fixed stride per tile)
    const __bf16* gsrc[5];
#pragma unroll
    for (int i = 0; i < 5; ++i) {
      const int c = wave + 4 * i;
      gsrc[i] = (c < 12) ? Kp + (size_t)lane * 96 + c * 8
                         : Vp + (size_t)lane * S_ + (c - 12) * 8;
    }
    auto stage = [&](int bsel) {
#pragma unroll
      for (int i = 0; i < 5; ++i) {
        const int c = wave + 4 * i;
        if (c < 12) {
          gll16(gsrc[i], &kbuf[bsel][c * 512]);
          gsrc[i] += 64 * 96;
        } else {
          gll16(gsrc[i], &vbuf[bsel][(c - 12) * 512]);
          gsrc[i] += 64;
        }
      }
    };

    stage(0);
    __syncthreads();

    int bsel = 0;
    for (int t = 0; t <= tMax; ++t) {
      if (t < tMax) stage(bsel ^ 1);
      if (t <= tEnd) {
        f32x16 s0 = fz16, s1 = fz16;
#pragma unroll
        for (int kd = 0; kd < 6; ++kd) {
          const int sl = kd * 2 + hi;
          bf16x8 a0 = *(const bf16x8*)&kbuf[bsel][(sl * 64 + lq) * 8];
          bf16x8 a1 = *(const bf16x8*)&kbuf[bsel][(sl * 64 + 32 + lq) * 8];
          s0 = mfma32(a0, qf[kd], s0);
          s1 = mfma32(a1, qf[kd], s1);
        }
        if (t == tEnd) {
          const int qg = q0w + lq;
          const int kvb = t * 64 + 4 * hi;
#pragma unroll
          for (int r = 0; r < 16; ++r) {
            const int crow = (r & 3) + 8 * (r >> 2);
            if (kvb + crow > qg) s0[r] = -3.0e38f;
            if (kvb + 32 + crow > qg) s1[r] = -3.0e38f;
          }
        }
        float tm = fmaxf(tmax16(s0), tmax16(s1));
        tm = fmaxf(tm, __shfl_xor(tm, 32));
        // defer-max (T13): rescale only when max grew by > 8 (log2 domain)
        if (!__all(tm <= m + 8.0f)) {
          const float mnew = fmaxf(m, tm);
          const float sc = exp2f(m - mnew);
          m = mnew;
          Lacc[0] *= sc;  // only reg 0 of Lacc is ever read
          o0 *= sc;
          o1 *= sc;
        }
        float p0[16], p1[16];
#pragma unroll
        for (int r = 0; r < 16; ++r) {
          p0[r] = exp2f(s0[r] - m);
          p1[r] = exp2f(s1[r] - m);
        }
        bf16x8 pa[4];
        pa[0] = packPA(hi, p0[0], p0[1], p0[2], p0[3], p0[4], p0[5], p0[6], p0[7]);
        pa[1] = packPA(hi, p0[8], p0[9], p0[10], p0[11], p0[12], p0[13], p0[14], p0[15]);
        pa[2] = packPA(hi, p1[0], p1[1], p1[2], p1[3], p1[4], p1[5], p1[6], p1[7]);
        pa[3] = packPA(hi, p1[8], p1[9], p1[10], p1[11], p1[12], p1[13], p1[14], p1[15]);
#pragma unroll
        for (int ks = 0; ks < 4; ++ks) {
          const int sl = ks * 2 + hi;
          bf16x8 v0 = *(const bf16x8*)&vbuf[bsel][(sl * 64 + lq) * 8];
          bf16x8 v1 = *(const bf16x8*)&vbuf[bsel][(sl * 64 + 32 + lq) * 8];
          o0 = mfma32(v0, pa[ks], o0);
          o1 = mfma32(v1, pa[ks], o1);
          Lacc = mfma32(onesA, pa[ks], Lacc);  // row-sum of P on the MFMA pipe
        }
      }
      __syncthreads();  // stage(t+1) complete + LDS reads of bsel done
      bsel ^= 1;
    }

    const float invL = 1.0f / Lacc[0];
    __bf16* aorow = ao + (size_t)(bb * S_ + q0w + lq) * 1024 + h * 64;
#pragma unroll
    for (int rr = 0; rr < 4; ++rr) {
      bf16x4 w0, w1;
#pragma unroll
      for (int jj = 0; jj < 4; ++jj) {
        w0[jj] = (__bf16)(o0[4 * rr + jj] * invL);
        w1[jj] = (__bf16)(o1[4 * rr + jj] * invL);
      }
      *(bf16x4*)&aorow[rr * 8 + 4 * hi] = w0;
      *(bf16x4*)&aorow[32 + rr * 8 + 4 * hi] = w1;
    }
  }
}

// ---------------- launcher ----------------
extern "C" void kernel_launch(void* const* d_in, const int* in_sizes, int n_in,
                              void* d_out, int out_size, void* d_ws, size_t ws_size,
                              hipStream_t stream) {
  (void)in_sizes; (void)n_in; (void)out_size; (void)ws_size;
  const float* x = (const float*)d_in[0];
  // d_in[1] = mask (tril ones) -> causal handled analytically
  const float* W_dkv = (const float*)d_in[2];
  const float* b_dkv = (const float*)d_in[3];
  const float* W_dq = (const float*)d_in[4];
  const float* b_dq = (const float*)d_in[5];
  const float* W_uk = (const float*)d_in[6];
  const float* b_uk = (const float*)d_in[7];
  const float* W_uv = (const float*)d_in[8];
  const float* b_uv = (const float*)d_in[9];
  const float* W_uq = (const float*)d_in[10];
  const float* b_uq = (const float*)d_in[11];
  const float* W_qr = (const float*)d_in[12];
  const float* b_qr = (const float*)d_in[13];
  const float* W_kr = (const float*)d_in[14];
  const float* b_kr = (const float*)d_in[15];
  const float* W_o = (const float*)d_in[16];
  const float* b_o = (const float*)d_in[17];
  float* out = (float*)d_out;

  char* ws = (char*)d_ws;
  size_t off = 0;
  auto take = [&](size_t nbytes) -> char* {
    char* p = ws + off;
    off += (nbytes + 255) & ~(size_t)255;
    return p;
  };
  __bf16* xb = (__bf16*)take((size_t)8192 * 1024 * 2);
  __bf16* WdT = (__bf16*)take((size_t)384 * 1024 * 2);     // [Wdq|Wdkv|Wkr|pad]^T
  __bf16* WuqT = (__bf16*)take((size_t)1536 * 128 * 2);    // [Wuq|Wqr]^T
  __bf16* WukvT = (__bf16*)take((size_t)2048 * 128 * 2);   // [Wuk|Wuv]^T
  __bf16* WoT = (__bf16*)take((size_t)1024 * 1024 * 2);
  float* bias_d = (float*)take(384 * 4);
  float* bias_uq = (float*)take(1536 * 4);
  float* bias_ukv = (float*)take(2048 * 4);
  float* ropec = (float*)take((size_t)S_ * 16 * 4);
  float* ropes = (float*)take((size_t)S_ * 16 * 4);
  __bf16* cqkvr = (__bf16*)take((size_t)8192 * 384 * 2);   // [c_q|c_kv|k_r|pad]
  __bf16* qr = (__bf16*)take((size_t)8192 * 512 * 2);      // raw q_r (pre-RoPE)
  __bf16* vv = (__bf16*)take((size_t)8192 * 1024 * 2);     // raw v
  __bf16* qt = (__bf16*)take((size_t)B_ * H_ * S_ * 96 * 2);
  __bf16* ktb = (__bf16*)take((size_t)B_ * H_ * S_ * 96 * 2);
  __bf16* vt = (__bf16*)take((size_t)B_ * H_ * 64 * S_ * 2);
  __bf16* aout = (__bf16*)take((size_t)8192 * 1024 * 2);

  // zero the padded rows of WdT (cols 288..383 of down-proj output)
  hipMemsetAsync(WdT + (size_t)288 * 1024, 0, (size_t)96 * 1024 * 2, stream);

  // fused prep: cvt_x + 8 transposes + rope tables + bias concat
  mla_prep<<<6000, 256, 0, stream>>>(x, xb, W_dq, W_dkv, W_kr, W_uq, W_qr, W_uk,
                                     W_uv, W_o, WdT, WuqT, WukvT, WoT, b_dq,
                                     b_dkv, b_kr, b_uq, b_qr, b_uk, b_uv, bias_d,
                                     bias_uq, bias_ukv, ropec, ropes);

  // down-proj: x(8192x1024) @ [Wdq|Wdkv|Wkr] -> cqkvr (8192x384)
  gemm32<0><<<dim3(3, 64), 256, 0, stream>>>(xb, 1024, WdT, 1024, bias_d,
                                             cqkvr, 384, 1024);
  // merged up-proj: c_q -> qt/qr ; c_kv -> ktb/vv
  gemm32up<<<dim3(28, 64), 256, 0, stream>>>(cqkvr, WuqT, WukvT, bias_uq,
                                             bias_ukv, qt, qr, ktb, vv);

  // fused glue: rope(q_r,k_r) -> qt/ktb + V -> V^T
  mla_glue<<<8192 + 2048, 256, 0, stream>>>(qr, cqkvr, ropec, ropes, qt, ktb, vv, vt);

  mla_attn<<<dim3(64, 8), 256, 0, stream>>>(qt, ktb, vt, aout);

  // final: aout(8192x1024) @ W_o + b_o -> out f32
  gemm32<1><<<dim3(8, 64), 256, 0, stream>>>(aout, 1024, WoT, 1024, b_o, out,
                                             1024, 1024);
}

// Round 10
// 336.627 us; speedup vs baseline: 1.2250x; 1.0096x over previous
//
#include <hip/hip_runtime.h>
#include <cstdint>
#include <cstddef>

#define S_ 2048
#define B_ 4
#define H_ 16
#define ALPHA_Q 0.14724394f  // SCALE * log2(e)

typedef __attribute__((ext_vector_type(8))) __bf16 bf16x8;
typedef __attribute__((ext_vector_type(4))) __bf16 bf16x4;
typedef __attribute__((ext_vector_type(4))) float f32x4;
typedef __attribute__((ext_vector_type(16))) float f32x16;

__device__ __forceinline__ f32x16 mfma32(bf16x8 a, bf16x8 b, f32x16 c) {
  return __builtin_amdgcn_mfma_f32_32x32x16_bf16(a, b, c, 0, 0, 0);
}

// async global->LDS, 16B per lane. LDS base must be wave-uniform (HW writes
// base + lane*16); global src is per-lane.
__device__ __forceinline__ void gll16(const void* g, void* l) {
  __builtin_amdgcn_global_load_lds(
      (__attribute__((address_space(1))) void*)(uintptr_t)g,
      (__attribute__((address_space(3))) void*)(uint32_t)(uintptr_t)l,
      16, 0, 0);
}

// v_cvt_pk_bf16_f32: packs (bf16(lo), bf16(hi)) into one dword (lo in bits 0-15)
__device__ __forceinline__ int cvtpk(float lo, float hi) {
  int r;
  asm("v_cvt_pk_bf16_f32 %0, %1, %2" : "=v"(r) : "v"(lo), "v"(hi));
  return r;
}

union PAU { int w[4]; bf16x8 v; };

// Build one 32x32x16 B-operand fragment of P^T (col=q=lane&31, k=8*hi+e)
// from 8 in-lane P values (crow order). Cross-half exchange via shfl_xor(32).
__device__ __forceinline__ bf16x8 packPA(int hi, float a0, float a1, float a2,
                                         float a3, float b0, float b1, float b2,
                                         float b3) {
  const int Ylo = cvtpk(a0, a1);
  const int Yhi = cvtpk(a2, a3);
  const int Xlo = cvtpk(b0, b1);
  const int Xhi = cvtpk(b2, b3);
  const int t0 = __shfl_xor(hi ? Ylo : Xlo, 32);
  const int t1 = __shfl_xor(hi ? Yhi : Xhi, 32);
  PAU u;
  u.w[0] = hi ? t0 : Ylo;
  u.w[1] = hi ? t1 : Yhi;
  u.w[2] = hi ? Xlo : t0;
  u.w[3] = hi ? Xhi : t1;
  return u.v;
}

// depth-5 tree max of one f32x16
__device__ __forceinline__ float tmax16(const f32x16& v) {
  float a[8];
#pragma unroll
  for (int i = 0; i < 8; ++i) a[i] = fmaxf(v[i], v[i + 8]);
#pragma unroll
  for (int s = 4; s > 0; s >>= 1)
#pragma unroll
    for (int i = 0; i < s; ++i) a[i] = fmaxf(a[i], a[i + s]);
  return a[0];
}

// ---------------- fused prep kernel ----------------
// tile-id dispatch: [0,4096) cvt_x ; [4096,5856) weight transposes ;
// [5856,5984) rope tables ; [5984,6000) bias concat.
__global__ __launch_bounds__(256) void mla_prep(
    const float* __restrict__ x, __bf16* __restrict__ xb,
    const float* __restrict__ W_dq, const float* __restrict__ W_dkv,
    const float* __restrict__ W_kr, const float* __restrict__ W_uq,
    const float* __restrict__ W_qr, const float* __restrict__ W_uk,
    const float* __restrict__ W_uv, const float* __restrict__ W_o,
    __bf16* __restrict__ WdT, __bf16* __restrict__ WuqT,
    __bf16* __restrict__ WukvT, __bf16* __restrict__ WoT,
    const float* __restrict__ b_dq, const float* __restrict__ b_dkv,
    const float* __restrict__ b_kr, const float* __restrict__ b_uq,
    const float* __restrict__ b_qr, const float* __restrict__ b_uk,
    const float* __restrict__ b_uv, float* __restrict__ bias_d,
    float* __restrict__ bias_uq, float* __restrict__ bias_ukv,
    float* __restrict__ ropec, float* __restrict__ ropes) {
  const int id = blockIdx.x;
  const int t = threadIdx.x;
  __shared__ float tile[32][33];

  if (id < 4096) {  // x f32 -> bf16
    const size_t i = ((size_t)id * 256 + t) * 8;
    float4 a = *(const float4*)&x[i];
    float4 b = *(const float4*)&x[i + 4];
    bf16x8 v;
    v[0] = (__bf16)a.x; v[1] = (__bf16)a.y; v[2] = (__bf16)a.z; v[3] = (__bf16)a.w;
    v[4] = (__bf16)b.x; v[5] = (__bf16)b.y; v[6] = (__bf16)b.z; v[7] = (__bf16)b.w;
    *(bf16x8*)&xb[i] = v;
    return;
  }
  if (id < 5856) {  // W (KxN f32) -> WT (NxK bf16)
    int rel = id - 4096;
    const float* W;
    __bf16* WT;
    int K, N, nt;
    if (rel < 128)      { W = W_dq;  WT = WdT;                      K = 1024; N = 128;  nt = 4; }
    else if (rel < 256) { W = W_dkv; WT = WdT + (size_t)128 * 1024; K = 1024; N = 128;  nt = 4;  rel -= 128; }
    else if (rel < 288) { W = W_kr;  WT = WdT + (size_t)256 * 1024; K = 1024; N = 32;   nt = 1;  rel -= 256; }
    else if (rel < 416) { W = W_uq;  WT = WuqT;                     K = 128;  N = 1024; nt = 32; rel -= 288; }
    else if (rel < 480) { W = W_qr;  WT = WuqT + (size_t)1024 * 128; K = 128; N = 512;  nt = 16; rel -= 416; }
    else if (rel < 608) { W = W_uk;  WT = WukvT;                    K = 128;  N = 1024; nt = 32; rel -= 480; }
    else if (rel < 736) { W = W_uv;  WT = WukvT + (size_t)1024 * 128; K = 128; N = 1024; nt = 32; rel -= 608; }
    else                { W = W_o;   WT = WoT;                      K = 1024; N = 1024; nt = 32; rel -= 736; }
    const int n0 = (rel % nt) * 32, k0 = (rel / nt) * 32;
    const int tx = t & 31, ty = t >> 5;
#pragma unroll
    for (int i = 0; i < 32; i += 8)
      tile[ty + i][tx] = W[(size_t)(k0 + ty + i) * N + n0 + tx];
    __syncthreads();
#pragma unroll
    for (int i = 0; i < 32; i += 8)
      WT[(size_t)(n0 + ty + i) * K + k0 + tx] = (__bf16)tile[tx][ty + i];
    return;
  }
  if (id < 5984) {  // rope tables
    const int g = (id - 5856) * 256 + t;  // < S_*16
    const int s = g >> 4, i = g & 15;
    const float inv = exp2f(-(float)i * (13.287712379549449f / 16.0f));
    const float ang = (float)s * inv;
    ropec[g] = cosf(ang);
    ropes[g] = sinf(ang);
    return;
  }
  {  // bias concat
    const int g = (id - 5984) * 256 + t;
    if (g < 384)
      bias_d[g] = (g < 128) ? b_dq[g] : (g < 256) ? b_dkv[g - 128]
                 : (g < 288) ? b_kr[g - 256] : 0.f;
    if (g < 1536) bias_uq[g] = (g < 1024) ? b_uq[g] : b_qr[g - 1024];
    if (g < 2048) bias_ukv[g] = (g < 1024) ? b_uk[g] : b_uv[g - 1024];
  }
}

// ---------------- mfma32 GEMM: C = A(MxK) * BT^T + bias ----------------
// 128x128 tile, BK=64, 4 waves 2x2 (each 64x64). MODE 0: bf16 out. 1: f32 out.
template <int MODE>
__global__ __launch_bounds__(256) void gemm32(
    const __bf16* __restrict__ A, int lda, const __bf16* __restrict__ BT, int ldbt,
    const float* __restrict__ bias, void* __restrict__ C0, int ldc, int K) {
  const int n0 = blockIdx.x * 128;
  const int m0 = blockIdx.y * 128;
  const int wave = threadIdx.x >> 6, lane = threadIdx.x & 63;
  const int hi = lane >> 5, lq = lane & 31;
  const int wm = (wave >> 1) * 64, wn = (wave & 1) * 64;
  __shared__ __bf16 __attribute__((aligned(16))) ldsA[8 * 128 * 8];  // 16 KB
  __shared__ __bf16 __attribute__((aligned(16))) ldsB[8 * 128 * 8];  // 16 KB

  const f32x16 fz16 = {0.f, 0.f, 0.f, 0.f, 0.f, 0.f, 0.f, 0.f,
                       0.f, 0.f, 0.f, 0.f, 0.f, 0.f, 0.f, 0.f};
  f32x16 acc00 = fz16, acc01 = fz16, acc10 = fz16, acc11 = fz16;

  for (int k0 = 0; k0 < K; k0 += 64) {
    __syncthreads();
#pragma unroll
    for (int i = 0; i < 8; ++i) {
      const int c = wave * 8 + i;
      if (c < 16) {
        const int sl = c >> 1, half = c & 1;
        gll16(&A[(size_t)(m0 + half * 64 + lane) * lda + k0 + sl * 8],
              &ldsA[(sl * 128 + half * 64) * 8]);
      } else {
        const int cc = c - 16;
        const int sl = cc >> 1, half = cc & 1;
        gll16(&BT[(size_t)(n0 + half * 64 + lane) * ldbt + k0 + sl * 8],
              &ldsB[(sl * 128 + half * 64) * 8]);
      }
    }
    __syncthreads();

#pragma unroll
    for (int ks = 0; ks < 4; ++ks) {
      const int sl = ks * 2 + hi;
      bf16x8 a0 = *(const bf16x8*)&ldsA[(sl * 128 + wm + lq) * 8];
      bf16x8 a1 = *(const bf16x8*)&ldsA[(sl * 128 + wm + 32 + lq) * 8];
      bf16x8 b0 = *(const bf16x8*)&ldsB[(sl * 128 + wn + lq) * 8];
      bf16x8 b1 = *(const bf16x8*)&ldsB[(sl * 128 + wn + 32 + lq) * 8];
      acc00 = mfma32(a0, b0, acc00);
      acc01 = mfma32(a0, b1, acc01);
      acc10 = mfma32(a1, b0, acc10);
      acc11 = mfma32(a1, b1, acc11);
    }
  }

  const f32x16* accs[2][2] = {{&acc00, &acc01}, {&acc10, &acc11}};
#pragma unroll
  for (int ni = 0; ni < 2; ++ni) {
    const int col = n0 + wn + ni * 32 + lq;
    const float bv = bias[col];
#pragma unroll
    for (int mi = 0; mi < 2; ++mi) {
      const f32x16& ac = *accs[mi][ni];
#pragma unroll
      for (int r = 0; r < 16; ++r) {
        const int row = m0 + wm + mi * 32 + (r & 3) + 8 * (r >> 2) + 4 * hi;
        const float v = ac[r] + bv;
        if (MODE == 0)
          ((__bf16*)C0)[(size_t)row * ldc + col] = (__bf16)v;
        else
          ((float*)C0)[(size_t)row * ldc + col] = v;
      }
    }
  }
}

// ---------------- merged up-proj GEMM (block-diagonal N) ----------------
// blockIdx.x < 12: up-q (c_q @ [Wuq|Wqr] -> qt scaled / qr raw)
// blockIdx.x >= 12: up-kv (c_kv @ [Wuk|Wuv] -> ktb / vv)
__global__ __launch_bounds__(256) void gemm32up(
    const __bf16* __restrict__ cqkvr, const __bf16* __restrict__ WuqT,
    const __bf16* __restrict__ WukvT, const float* __restrict__ bias_uq,
    const float* __restrict__ bias_ukv, __bf16* __restrict__ qt,
    __bf16* __restrict__ qr, __bf16* __restrict__ ktb, __bf16* __restrict__ vv) {
  const bool isQ = blockIdx.x < 12;
  const int n0 = (isQ ? blockIdx.x : (blockIdx.x - 12)) * 128;
  const __bf16* A = cqkvr + (isQ ? 0 : 128);
  const __bf16* BT = isQ ? WuqT : WukvT;
  const float* bias = isQ ? bias_uq : bias_ukv;
  const int m0 = blockIdx.y * 128;
  const int wave = threadIdx.x >> 6, lane = threadIdx.x & 63;
  const int hi = lane >> 5, lq = lane & 31;
  const int wm = (wave >> 1) * 64, wn = (wave & 1) * 64;
  __shared__ __bf16 __attribute__((aligned(16))) ldsA[8 * 128 * 8];
  __shared__ __bf16 __attribute__((aligned(16))) ldsB[8 * 128 * 8];

  const f32x16 fz16 = {0.f, 0.f, 0.f, 0.f, 0.f, 0.f, 0.f, 0.f,
                       0.f, 0.f, 0.f, 0.f, 0.f, 0.f, 0.f, 0.f};
  f32x16 acc00 = fz16, acc01 = fz16, acc10 = fz16, acc11 = fz16;

  for (int k0 = 0; k0 < 128; k0 += 64) {
    __syncthreads();
#pragma unroll
    for (int i = 0; i < 8; ++i) {
      const int c = wave * 8 + i;
      if (c < 16) {
        const int sl = c >> 1, half = c & 1;
        gll16(&A[(size_t)(m0 + half * 64 + lane) * 384 + k0 + sl * 8],
              &ldsA[(sl * 128 + half * 64) * 8]);
      } else {
        const int cc = c - 16;
        const int sl = cc >> 1, half = cc & 1;
        gll16(&BT[(size_t)(n0 + half * 64 + lane) * 128 + k0 + sl * 8],
              &ldsB[(sl * 128 + half * 64) * 8]);
      }
    }
    __syncthreads();

#pragma unroll
    for (int ks = 0; ks < 4; ++ks) {
      const int sl = ks * 2 + hi;
      bf16x8 a0 = *(const bf16x8*)&ldsA[(sl * 128 + wm + lq) * 8];
      bf16x8 a1 = *(const bf16x8*)&ldsA[(sl * 128 + wm + 32 + lq) * 8];
      bf16x8 b0 = *(const bf16x8*)&ldsB[(sl * 128 + wn + lq) * 8];
      bf16x8 b1 = *(const bf16x8*)&ldsB[(sl * 128 + wn + 32 + lq) * 8];
      acc00 = mfma32(a0, b0, acc00);
      acc01 = mfma32(a0, b1, acc01);
      acc10 = mfma32(a1, b0, acc10);
      acc11 = mfma32(a1, b1, acc11);
    }
  }

  const f32x16* accs[2][2] = {{&acc00, &acc01}, {&acc10, &acc11}};
#pragma unroll
  for (int ni = 0; ni < 2; ++ni) {
    const int col = n0 + wn + ni * 32 + lq;
    const float bv = bias[col];
#pragma unroll
    for (int mi = 0; mi < 2; ++mi) {
      const f32x16& ac = *accs[mi][ni];
#pragma unroll
      for (int r = 0; r < 16; ++r) {
        const int row = m0 + wm + mi * 32 + (r & 3) + 8 * (r >> 2) + 4 * hi;
        const float v = ac[r] + bv;
        const int b = row >> 11, s = row & 2047;
        if (col < 1024) {
          const int h = col >> 6, d = col & 63;
          const size_t o = ((size_t)(b * H_ + h) * S_ + s) * 96 + d;
          if (isQ)
            qt[o] = (__bf16)(v * ALPHA_Q);
          else
            ktb[o] = (__bf16)v;
        } else {
          if (isQ)
            qr[(size_t)row * 512 + col - 1024] = (__bf16)v;
          else
            vv[(size_t)row * 1024 + col - 1024] = (__bf16)v;
        }
      }
    }
  }
}

// ---------------- fused glue: RoPE(q_r,k_r) + V transpose ----------------
__global__ __launch_bounds__(256) void mla_glue(
    const __bf16* __restrict__ qr, const __bf16* __restrict__ cqkvr,
    const float* __restrict__ ropec, const float* __restrict__ ropes,
    __bf16* __restrict__ qt, __bf16* __restrict__ ktb,
    const __bf16* __restrict__ vv, __bf16* __restrict__ vt) {
  __shared__ __bf16 __attribute__((aligned(16))) tile[64][72];
  const int t = threadIdx.x;
  if (blockIdx.x < 8192) {
    const int gid = blockIdx.x * 256 + t;
    const int bs = gid >> 8;
    const int h = (gid >> 4) & 15;
    const int i = gid & 15;
    const int b = bs >> 11, s = bs & 2047;
    const float c = ropec[s * 16 + i], sn = ropes[s * 16 + i];
    const size_t o = ((size_t)(b * H_ + h) * S_ + s) * 96 + 64 + 2 * i;
    {
      const float r = (float)qr[(size_t)bs * 512 + h * 32 + 2 * i];
      const float im = (float)qr[(size_t)bs * 512 + h * 32 + 2 * i + 1];
      qt[o] = (__bf16)((r * c - im * sn) * ALPHA_Q);
      qt[o + 1] = (__bf16)((r * sn + im * c) * ALPHA_Q);
    }
    {
      const float r = (float)cqkvr[(size_t)bs * 384 + 256 + 2 * i];
      const float im = (float)cqkvr[(size_t)bs * 384 + 256 + 2 * i + 1];
      ktb[o] = (__bf16)(r * c - im * sn);
      ktb[o + 1] = (__bf16)(r * sn + im * c);
    }
    return;
  }
  const int bid = blockIdx.x - 8192;
  const int s0 = (bid & 31) * 64;
  const int bh = bid >> 5;
  const int b = bh >> 4, h = bh & 15;
  {
    const int r = t >> 2, c0 = (t & 3) * 16;
    const size_t src = (size_t)(b * S_ + s0 + r) * 1024 + h * 64 + c0;
    bf16x8 u0 = *(const bf16x8*)&vv[src];
    bf16x8 u1 = *(const bf16x8*)&vv[src + 8];
    *(bf16x8*)&tile[r][c0] = u0;
    *(bf16x8*)&tile[r][c0 + 8] = u1;
  }
  __syncthreads();
  {
    const int d = t >> 2, sc0 = (t & 3) * 16;
    bf16x8 w0, w1;
#pragma unroll
    for (int e = 0; e < 8; ++e) {
      w0[e] = tile[sc0 + e][d];
      w1[e] = tile[sc0 + 8 + e][d];
    }
    const size_t dst = ((size_t)bh * 64 + d) * S_ + s0 + sc0;
    *(bf16x8*)&vt[dst] = w0;
    *(bf16x8*)&vt[dst + 8] = w1;
  }
}

// ---------------- causal flash attention (32x32 MFMA, dual-q per wave) -----
// grid (B*H=64, 8): bh = blockIdx.x -> bid%8 = bh%8 -> all 8 j-blocks of a bh
// share one XCD L2 (T1, FETCH 186->53MB verified R9).
// DUAL-Q: block j processes q-blocks A=j and B=15-j against the SAME staged
// K/V tile stream (tiles 0..31-2j staged once). Two independent MFMA+softmax
// chains per iteration give 2x ILP (the latency hiding 2 waves/SIMD can't);
// ~26% fewer staged tiles + barriers. Compute per block uniform (34 units).
__global__ __launch_bounds__(256, 2) void mla_attn(const __bf16* __restrict__ qt,
                                                   const __bf16* __restrict__ kt,
                                                   const __bf16* __restrict__ vt,
                                                   __bf16* __restrict__ ao) {
  const int bh = blockIdx.x;
  const int j = blockIdx.y;  // 0..7
  const int wave = threadIdx.x >> 6, lane = threadIdx.x & 63;
  const int hi = lane >> 5, lq = lane & 31;
  const __bf16* Q = qt + (size_t)bh * S_ * 96;
  const __bf16* Kp = kt + (size_t)bh * S_ * 96;
  const __bf16* Vp = vt + (size_t)bh * 64 * S_;
  const int bb = bh >> 4, h = bh & 15;

  __shared__ __bf16 __attribute__((aligned(16))) kbuf[2][12 * 512];
  __shared__ __bf16 __attribute__((aligned(16))) vbuf[2][8 * 512];

  const f32x16 fz16 = {0.f, 0.f, 0.f, 0.f, 0.f, 0.f, 0.f, 0.f,
                       0.f, 0.f, 0.f, 0.f, 0.f, 0.f, 0.f, 0.f};
  bf16x8 onesA;
#pragma unroll
  for (int e = 0; e < 8; ++e) onesA[e] = (__bf16)1.0f;

  const int qblkA = j, qblkB = 15 - j;
  const int q0wA = qblkA * 128 + wave * 32;
  const int q0wB = qblkB * 128 + wave * 32;

  bf16x8 qfA[6], qfB[6];
#pragma unroll
  for (int kd = 0; kd < 6; ++kd) {
    qfA[kd] = *(const bf16x8*)&Q[(size_t)(q0wA + lq) * 96 + kd * 16 + hi * 8];
    qfB[kd] = *(const bf16x8*)&Q[(size_t)(q0wB + lq) * 96 + kd * 16 + hi * 8];
  }

  f32x16 o0A = fz16, o1A = fz16, LA = fz16;
  f32x16 o0B = fz16, o1B = fz16, LB = fz16;
  float mA = -3.0e38f, mB = -3.0e38f;

  const int tEndA = (q0wA + 31) >> 6;
  const int tEndB = (q0wB + 31) >> 6;
  const int tMax = qblkB * 2 + 1;  // covers all waves' tEndB

  // per-wave staging base pointers (advance by fixed stride per tile)
  const __bf16* gsrc[5];
#pragma unroll
  for (int i = 0; i < 5; ++i) {
    const int c = wave + 4 * i;
    gsrc[i] = (c < 12) ? Kp + (size_t)lane * 96 + c * 8
                       : Vp + (size_t)lane * S_ + (c - 12) * 8;
  }
  auto stage = [&](int bsel) {
#pragma unroll
    for (int i = 0; i < 5; ++i) {
      const int c = wave + 4 * i;
      if (c < 12) {
        gll16(gsrc[i], &kbuf[bsel][c * 512]);
        gsrc[i] += 64 * 96;
      } else {
        gll16(gsrc[i], &vbuf[bsel][(c - 12) * 512]);
        gsrc[i] += 64;
      }
    }
  };

  // one q-block's QK^T + softmax + PV against the tile in buffers [bsel]
  auto process = [&](const bf16x8* qf, f32x16& o0, f32x16& o1, f32x16& Lacc,
                     float& m, int q0w, int tEnd, int t, int bsel) {
    f32x16 s0 = fz16, s1 = fz16;
#pragma unroll
    for (int kd = 0; kd < 6; ++kd) {
      const int sl = kd * 2 + hi;
      bf16x8 a0 = *(const bf16x8*)&kbuf[bsel][(sl * 64 + lq) * 8];
      bf16x8 a1 = *(const bf16x8*)&kbuf[bsel][(sl * 64 + 32 + lq) * 8];
      s0 = mfma32(a0, qf[kd], s0);
      s1 = mfma32(a1, qf[kd], s1);
    }
    if (t == tEnd) {
      const int qg = q0w + lq;
      const int kvb = t * 64 + 4 * hi;
#pragma unroll
      for (int r = 0; r < 16; ++r) {
        const int crow = (r & 3) + 8 * (r >> 2);
        if (kvb + crow > qg) s0[r] = -3.0e38f;
        if (kvb + 32 + crow > qg) s1[r] = -3.0e38f;
      }
    }
    float tm = fmaxf(tmax16(s0), tmax16(s1));
    tm = fmaxf(tm, __shfl_xor(tm, 32));
    // defer-max (T13): rescale only when max grew by > 8 (log2 domain)
    if (!__all(tm <= m + 8.0f)) {
      const float mnew = fmaxf(m, tm);
      const float sc = exp2f(m - mnew);
      m = mnew;
      Lacc[0] *= sc;  // only reg 0 of Lacc is ever read
      o0 *= sc;
      o1 *= sc;
    }
    float p0[16], p1[16];
#pragma unroll
    for (int r = 0; r < 16; ++r) {
      p0[r] = exp2f(s0[r] - m);
      p1[r] = exp2f(s1[r] - m);
    }
    bf16x8 pa[4];
    pa[0] = packPA(hi, p0[0], p0[1], p0[2], p0[3], p0[4], p0[5], p0[6], p0[7]);
    pa[1] = packPA(hi, p0[8], p0[9], p0[10], p0[11], p0[12], p0[13], p0[14], p0[15]);
    pa[2] = packPA(hi, p1[0], p1[1], p1[2], p1[3], p1[4], p1[5], p1[6], p1[7]);
    pa[3] = packPA(hi, p1[8], p1[9], p1[10], p1[11], p1[12], p1[13], p1[14], p1[15]);
#pragma unroll
    for (int ks = 0; ks < 4; ++ks) {
      const int sl = ks * 2 + hi;
      bf16x8 v0 = *(const bf16x8*)&vbuf[bsel][(sl * 64 + lq) * 8];
      bf16x8 v1 = *(const bf16x8*)&vbuf[bsel][(sl * 64 + 32 + lq) * 8];
      o0 = mfma32(v0, pa[ks], o0);
      o1 = mfma32(v1, pa[ks], o1);
      Lacc = mfma32(onesA, pa[ks], Lacc);  // row-sum of P on the MFMA pipe
    }
  };

  stage(0);
  __syncthreads();

  int bsel = 0;
  for (int t = 0; t <= tMax; ++t) {
    if (t < tMax) stage(bsel ^ 1);
    if (t <= tEndA) process(qfA, o0A, o1A, LA, mA, q0wA, tEndA, t, bsel);
    if (t <= tEndB) process(qfB, o0B, o1B, LB, mB, q0wB, tEndB, t, bsel);
    __syncthreads();  // stage(t+1) complete + LDS reads of bsel done
    bsel ^= 1;
  }

  auto writeOut = [&](const f32x16& o0, const f32x16& o1, const f32x16& Lacc,
                      int q0w) {
    const float invL = 1.0f / Lacc[0];
    __bf16* aorow = ao + (size_t)(bb * S_ + q0w + lq) * 1024 + h * 64;
#pragma unroll
    for (int rr = 0; rr < 4; ++rr) {
      bf16x4 w0, w1;
#pragma unroll
      for (int jj = 0; jj < 4; ++jj) {
        w0[jj] = (__bf16)(o0[4 * rr + jj] * invL);
        w1[jj] = (__bf16)(o1[4 * rr + jj] * invL);
      }
      *(bf16x4*)&aorow[rr * 8 + 4 * hi] = w0;
      *(bf16x4*)&aorow[32 + rr * 8 + 4 * hi] = w1;
    }
  };
  writeOut(o0A, o1A, LA, q0wA);
  writeOut(o0B, o1B, LB, q0wB);
}

// ---------------- launcher ----------------
extern "C" void kernel_launch(void* const* d_in, const int* in_sizes, int n_in,
                              void* d_out, int out_size, void* d_ws, size_t ws_size,
                              hipStream_t stream) {
  (void)in_sizes; (void)n_in; (void)out_size; (void)ws_size;
  const float* x = (const float*)d_in[0];
  // d_in[1] = mask (tril ones) -> causal handled analytically
  const float* W_dkv = (const float*)d_in[2];
  const float* b_dkv = (const float*)d_in[3];
  const float* W_dq = (const float*)d_in[4];
  const float* b_dq = (const float*)d_in[5];
  const float* W_uk = (const float*)d_in[6];
  const float* b_uk = (const float*)d_in[7];
  const float* W_uv = (const float*)d_in[8];
  const float* b_uv = (const float*)d_in[9];
  const float* W_uq = (const float*)d_in[10];
  const float* b_uq = (const float*)d_in[11];
  const float* W_qr = (const float*)d_in[12];
  const float* b_qr = (const float*)d_in[13];
  const float* W_kr = (const float*)d_in[14];
  const float* b_kr = (const float*)d_in[15];
  const float* W_o = (const float*)d_in[16];
  const float* b_o = (const float*)d_in[17];
  float* out = (float*)d_out;

  char* ws = (char*)d_ws;
  size_t off = 0;
  auto take = [&](size_t nbytes) -> char* {
    char* p = ws + off;
    off += (nbytes + 255) & ~(size_t)255;
    return p;
  };
  __bf16* xb = (__bf16*)take((size_t)8192 * 1024 * 2);
  __bf16* WdT = (__bf16*)take((size_t)384 * 1024 * 2);     // [Wdq|Wdkv|Wkr|pad]^T
  __bf16* WuqT = (__bf16*)take((size_t)1536 * 128 * 2);    // [Wuq|Wqr]^T
  __bf16* WukvT = (__bf16*)take((size_t)2048 * 128 * 2);   // [Wuk|Wuv]^T
  __bf16* WoT = (__bf16*)take((size_t)1024 * 1024 * 2);
  float* bias_d = (float*)take(384 * 4);
  float* bias_uq = (float*)take(1536 * 4);
  float* bias_ukv = (float*)take(2048 * 4);
  float* ropec = (float*)take((size_t)S_ * 16 * 4);
  float* ropes = (float*)take((size_t)S_ * 16 * 4);
  __bf16* cqkvr = (__bf16*)take((size_t)8192 * 384 * 2);   // [c_q|c_kv|k_r|pad]
  __bf16* qr = (__bf16*)take((size_t)8192 * 512 * 2);      // raw q_r (pre-RoPE)
  __bf16* vv = (__bf16*)take((size_t)8192 * 1024 * 2);     // raw v
  __bf16* qt = (__bf16*)take((size_t)B_ * H_ * S_ * 96 * 2);
  __bf16* ktb = (__bf16*)take((size_t)B_ * H_ * S_ * 96 * 2);
  __bf16* vt = (__bf16*)take((size_t)B_ * H_ * 64 * S_ * 2);
  __bf16* aout = (__bf16*)take((size_t)8192 * 1024 * 2);

  // zero the padded rows of WdT (cols 288..383 of down-proj output)
  hipMemsetAsync(WdT + (size_t)288 * 1024, 0, (size_t)96 * 1024 * 2, stream);

  // fused prep: cvt_x + 8 transposes + rope tables + bias concat
  mla_prep<<<6000, 256, 0, stream>>>(x, xb, W_dq, W_dkv, W_kr, W_uq, W_qr, W_uk,
                                     W_uv, W_o, WdT, WuqT, WukvT, WoT, b_dq,
                                     b_dkv, b_kr, b_uq, b_qr, b_uk, b_uv, bias_d,
                                     bias_uq, bias_ukv, ropec, ropes);

  // down-proj: x(8192x1024) @ [Wdq|Wdkv|Wkr] -> cqkvr (8192x384)
  gemm32<0><<<dim3(3, 64), 256, 0, stream>>>(xb, 1024, WdT, 1024, bias_d,
                                             cqkvr, 384, 1024);
  // merged up-proj: c_q -> qt/qr ; c_kv -> ktb/vv
  gemm32up<<<dim3(28, 64), 256, 0, stream>>>(cqkvr, WuqT, WukvT, bias_uq,
                                             bias_ukv, qt, qr, ktb, vv);

  // fused glue: rope(q_r,k_r) -> qt/ktb + V -> V^T
  mla_glue<<<8192 + 2048, 256, 0, stream>>>(qr, cqkvr, ropec, ropes, qt, ktb, vv, vt);

  mla_attn<<<dim3(64, 8), 256, 0, stream>>>(qt, ktb, vt, aout);

  // final: aout(8192x1024) @ W_o + b_o -> out f32
  gemm32<1><<<dim3(8, 64), 256, 0, stream>>>(aout, 1024, WoT, 1024, b_o, out,
                                             1024, 1024);
}